// Round 1
// baseline (1072.511 us; speedup 1.0000x reference)
//
#include <hip/hip_runtime.h>

#define N_USERS 100000
#define N_ITEMS 400000
#define N_NODES 500000
#define EMB_DIM 64
#define N_EDGES 1200000
#define N_LAYERS 3

// acc = 0.25 * x0 ; xcur = x0  (x0 = concat(user_w, item_w))
__global__ void lgcn_init(const float* __restrict__ user_w,
                          const float* __restrict__ item_w,
                          float* __restrict__ acc,
                          float* __restrict__ xcur) {
    const long long total4 = (long long)N_NODES * EMB_DIM / 4;
    const long long user4  = (long long)N_USERS * EMB_DIM / 4;
    const float4* uw = (const float4*)user_w;
    const float4* iw = (const float4*)item_w;
    float4* a4 = (float4*)acc;
    float4* x4 = (float4*)xcur;
    long long stride = (long long)gridDim.x * blockDim.x;
    for (long long i = (long long)blockIdx.x * blockDim.x + threadIdx.x;
         i < total4; i += stride) {
        float4 v = (i < user4) ? uw[i] : iw[i - user4];
        x4[i] = v;
        a4[i] = make_float4(0.25f * v.x, 0.25f * v.y, 0.25f * v.z, 0.25f * v.w);
    }
}

// xnext = 0
__global__ void lgcn_zero(float* __restrict__ p) {
    const long long total4 = (long long)N_NODES * EMB_DIM / 4;
    float4* p4 = (float4*)p;
    long long stride = (long long)gridDim.x * blockDim.x;
    float4 z = make_float4(0.f, 0.f, 0.f, 0.f);
    for (long long i = (long long)blockIdx.x * blockDim.x + threadIdx.x;
         i < total4; i += stride) {
        p4[i] = z;
    }
}

// xnext[dst] += xcur[src] * w   (64 threads per edge, one dim each)
__global__ void lgcn_scatter(const float* __restrict__ xcur,
                             const int* __restrict__ src,
                             const int* __restrict__ dst,
                             const float* __restrict__ w,
                             float* __restrict__ xnext) {
    const int groups_per_block = blockDim.x >> 6;          // 64 threads per edge
    const int d = threadIdx.x & 63;
    int eg = blockIdx.x * groups_per_block + (threadIdx.x >> 6);
    const int estride = gridDim.x * groups_per_block;
    for (int e = eg; e < N_EDGES; e += estride) {
        int s = src[e];
        int t = dst[e];
        float wt = w[e];
        float val = xcur[(long long)s * EMB_DIM + d] * wt;
        atomicAdd(&xnext[(long long)t * EMB_DIM + d], val);
    }
}

// acc += 0.25 * xn
__global__ void lgcn_accadd(const float* __restrict__ xn,
                            float* __restrict__ acc) {
    const long long total4 = (long long)N_NODES * EMB_DIM / 4;
    const float4* x4 = (const float4*)xn;
    float4* a4 = (float4*)acc;
    long long stride = (long long)gridDim.x * blockDim.x;
    for (long long i = (long long)blockIdx.x * blockDim.x + threadIdx.x;
         i < total4; i += stride) {
        float4 v = x4[i];
        float4 a = a4[i];
        a.x += 0.25f * v.x; a.y += 0.25f * v.y;
        a.z += 0.25f * v.z; a.w += 0.25f * v.w;
        a4[i] = a;
    }
}

extern "C" void kernel_launch(void* const* d_in, const int* in_sizes, int n_in,
                              void* d_out, int out_size, void* d_ws, size_t ws_size,
                              hipStream_t stream) {
    const float* user_w = (const float*)d_in[0];
    const float* item_w = (const float*)d_in[1];
    const int*   eidx   = (const int*)d_in[2];     // [2, N_EDGES] int32
    const float* ew     = (const float*)d_in[3];   // [N_EDGES]
    const int* src = eidx;
    const int* dst = eidx + N_EDGES;

    float* acc   = (float*)d_out;                  // [N_NODES, EMB_DIM]
    float* xcur  = (float*)d_ws;                   // [N_NODES, EMB_DIM]
    float* xnext = xcur + (long long)N_NODES * EMB_DIM;

    const int blk = 256;
    const int grid_elem = 2048;   // grid-stride elementwise
    const int grid_scat = 4096;   // 4096 blocks * 4 edge-groups

    lgcn_init<<<grid_elem, blk, 0, stream>>>(user_w, item_w, acc, xcur);

    for (int layer = 0; layer < N_LAYERS; ++layer) {
        lgcn_zero<<<grid_elem, blk, 0, stream>>>(xnext);
        lgcn_scatter<<<grid_scat, blk, 0, stream>>>(xcur, src, dst, ew, xnext);
        lgcn_accadd<<<grid_elem, blk, 0, stream>>>(xnext, acc);
        float* tmp = xcur; xcur = xnext; xnext = tmp;
    }
}

// Round 2
// 854.845 us; speedup vs baseline: 1.2546x; 1.2546x over previous
//
#include <hip/hip_runtime.h>

#define N_USERS 100000
#define N_ITEMS 400000
#define N_NODES 500000
#define EMB_DIM 64
#define N_EDGES 1200000
#define N_LAYERS 3

typedef long long ll;

// ---------------------------------------------------------------------------
// CSR build: counts -> 2-level exclusive scan -> fill (csr_src, csr_w)
// ---------------------------------------------------------------------------

__global__ void k_zero_int(int* __restrict__ p, int n) {
    int stride = gridDim.x * blockDim.x;
    for (int i = blockIdx.x * blockDim.x + threadIdx.x; i < n; i += stride)
        p[i] = 0;
}

__global__ void k_count(const int* __restrict__ dst, int* __restrict__ cnt) {
    int stride = gridDim.x * blockDim.x;
    for (int e = blockIdx.x * blockDim.x + threadIdx.x; e < N_EDGES; e += stride)
        atomicAdd(&cnt[dst[e]], 1);
}

// scan1: per-block (256 thr x 4 elems = 1024) exclusive scan in place,
// block total -> blocksums[b]
#define SCAN_ELEMS 1024
__global__ void k_scan1(int* __restrict__ data, int* __restrict__ blocksums) {
    __shared__ int tmp[256];
    int b = blockIdx.x;
    int t = threadIdx.x;
    int base = b * SCAN_ELEMS + t * 4;
    int v[4];
    #pragma unroll
    for (int k = 0; k < 4; ++k) {
        int i = base + k;
        v[k] = (i < N_NODES) ? data[i] : 0;
    }
    int tsum = v[0] + v[1] + v[2] + v[3];
    tmp[t] = tsum;
    __syncthreads();
    // Hillis-Steele inclusive scan over 256 thread sums
    for (int off = 1; off < 256; off <<= 1) {
        int x = (t >= off) ? tmp[t - off] : 0;
        __syncthreads();
        tmp[t] += x;
        __syncthreads();
    }
    int texcl = tmp[t] - tsum;     // exclusive prefix for this thread
    int run = texcl;
    #pragma unroll
    for (int k = 0; k < 4; ++k) {
        int i = base + k;
        if (i < N_NODES) data[i] = run;
        run += v[k];
    }
    if (t == 255) blocksums[b] = tmp[255];
}

// scan2: single block, exclusive scan of nb block sums (nb <= 512)
__global__ void k_scan2(int* __restrict__ blocksums, int nb) {
    __shared__ int tmp[512];
    int t = threadIdx.x;
    int v = (t < nb) ? blocksums[t] : 0;
    tmp[t] = v;
    __syncthreads();
    for (int off = 1; off < 512; off <<= 1) {
        int x = (t >= off) ? tmp[t - off] : 0;
        __syncthreads();
        tmp[t] += x;
        __syncthreads();
    }
    if (t < nb) blocksums[t] = tmp[t] - v;   // exclusive
}

// scan3: add block offsets, copy to cursor, finalize rowptr[N_NODES]
__global__ void k_scan3(int* __restrict__ rowptr, const int* __restrict__ blocksums,
                        int* __restrict__ cursor) {
    int stride = gridDim.x * blockDim.x;
    for (int i = blockIdx.x * blockDim.x + threadIdx.x; i < N_NODES; i += stride) {
        int v = rowptr[i] + blocksums[i >> 10];
        rowptr[i] = v;
        cursor[i] = v;
    }
    if (blockIdx.x == 0 && threadIdx.x == 0) rowptr[N_NODES] = N_EDGES;
}

__global__ void k_fill(const int* __restrict__ src, const int* __restrict__ dst,
                       const float* __restrict__ w,
                       int* __restrict__ cursor,
                       int* __restrict__ csr_src, float* __restrict__ csr_w) {
    int stride = gridDim.x * blockDim.x;
    for (int e = blockIdx.x * blockDim.x + threadIdx.x; e < N_EDGES; e += stride) {
        int t = dst[e];
        int pos = atomicAdd(&cursor[t], 1);
        csr_src[pos] = src[e];
        csr_w[pos] = w[e];
    }
}

// ---------------------------------------------------------------------------
// Layer kernels: one wave (64 lanes) per node, lane = embedding dim.
// ---------------------------------------------------------------------------

// Layer 1: gather from the split embedding tables; write x1 and
// acc = 0.25*(x0 + x1).
__global__ void k_layer1(const float* __restrict__ user_w,
                         const float* __restrict__ item_w,
                         const int* __restrict__ rowptr,
                         const int* __restrict__ csr_src,
                         const float* __restrict__ csr_w,
                         float* __restrict__ xout,
                         float* __restrict__ acc) {
    int wave = (blockIdx.x * blockDim.x + threadIdx.x) >> 6;
    int nwaves = (gridDim.x * blockDim.x) >> 6;
    int d = threadIdx.x & 63;
    for (int n = wave; n < N_NODES; n += nwaves) {
        int start = rowptr[n];
        int end = rowptr[n + 1];
        float s = 0.f;
        for (int j = start; j < end; ++j) {
            int si = csr_src[j];
            float wt = csr_w[j];
            const float* xr = (si < N_USERS)
                ? (user_w + (ll)si * EMB_DIM)
                : (item_w + (ll)(si - N_USERS) * EMB_DIM);
            s += xr[d] * wt;
        }
        float x0v = (n < N_USERS)
            ? user_w[(ll)n * EMB_DIM + d]
            : item_w[(ll)(n - N_USERS) * EMB_DIM + d];
        ll idx = (ll)n * EMB_DIM + d;
        xout[idx] = s;
        acc[idx] = 0.25f * (x0v + s);
    }
}

// Layers 2..L: gather from xin; acc += 0.25*s; optionally write xout.
__global__ void k_layerN(const float* __restrict__ xin,
                         const int* __restrict__ rowptr,
                         const int* __restrict__ csr_src,
                         const float* __restrict__ csr_w,
                         float* __restrict__ xout,   // may be null
                         float* __restrict__ acc) {
    int wave = (blockIdx.x * blockDim.x + threadIdx.x) >> 6;
    int nwaves = (gridDim.x * blockDim.x) >> 6;
    int d = threadIdx.x & 63;
    for (int n = wave; n < N_NODES; n += nwaves) {
        int start = rowptr[n];
        int end = rowptr[n + 1];
        float s = 0.f;
        for (int j = start; j < end; ++j) {
            int si = csr_src[j];
            float wt = csr_w[j];
            s += xin[(ll)si * EMB_DIM + d] * wt;
        }
        ll idx = (ll)n * EMB_DIM + d;
        if (xout) xout[idx] = s;
        acc[idx] += 0.25f * s;
    }
}

// ---------------------------------------------------------------------------
// Fallback (round-1 atomic path) in case ws is too small for CSR arrays.
// ---------------------------------------------------------------------------

__global__ void fb_init(const float* __restrict__ user_w,
                        const float* __restrict__ item_w,
                        float* __restrict__ acc, float* __restrict__ xcur) {
    const ll total4 = (ll)N_NODES * EMB_DIM / 4;
    const ll user4 = (ll)N_USERS * EMB_DIM / 4;
    const float4* uw = (const float4*)user_w;
    const float4* iw = (const float4*)item_w;
    float4* a4 = (float4*)acc;
    float4* x4 = (float4*)xcur;
    ll stride = (ll)gridDim.x * blockDim.x;
    for (ll i = (ll)blockIdx.x * blockDim.x + threadIdx.x; i < total4; i += stride) {
        float4 v = (i < user4) ? uw[i] : iw[i - user4];
        x4[i] = v;
        a4[i] = make_float4(0.25f * v.x, 0.25f * v.y, 0.25f * v.z, 0.25f * v.w);
    }
}
__global__ void fb_zero(float* __restrict__ p) {
    const ll total4 = (ll)N_NODES * EMB_DIM / 4;
    float4* p4 = (float4*)p;
    ll stride = (ll)gridDim.x * blockDim.x;
    float4 z = make_float4(0.f, 0.f, 0.f, 0.f);
    for (ll i = (ll)blockIdx.x * blockDim.x + threadIdx.x; i < total4; i += stride)
        p4[i] = z;
}
__global__ void fb_scatter(const float* __restrict__ xcur, const int* __restrict__ src,
                           const int* __restrict__ dst, const float* __restrict__ w,
                           float* __restrict__ xnext) {
    const int gpb = blockDim.x >> 6;
    const int d = threadIdx.x & 63;
    int eg = blockIdx.x * gpb + (threadIdx.x >> 6);
    const int estride = gridDim.x * gpb;
    for (int e = eg; e < N_EDGES; e += estride) {
        int s = src[e]; int t = dst[e]; float wt = w[e];
        atomicAdd(&xnext[(ll)t * EMB_DIM + d], xcur[(ll)s * EMB_DIM + d] * wt);
    }
}
__global__ void fb_accadd(const float* __restrict__ xn, float* __restrict__ acc) {
    const ll total4 = (ll)N_NODES * EMB_DIM / 4;
    const float4* x4 = (const float4*)xn;
    float4* a4 = (float4*)acc;
    ll stride = (ll)gridDim.x * blockDim.x;
    for (ll i = (ll)blockIdx.x * blockDim.x + threadIdx.x; i < total4; i += stride) {
        float4 v = x4[i]; float4 a = a4[i];
        a.x += 0.25f * v.x; a.y += 0.25f * v.y;
        a.z += 0.25f * v.z; a.w += 0.25f * v.w;
        a4[i] = a;
    }
}

// ---------------------------------------------------------------------------

extern "C" void kernel_launch(void* const* d_in, const int* in_sizes, int n_in,
                              void* d_out, int out_size, void* d_ws, size_t ws_size,
                              hipStream_t stream) {
    const float* user_w = (const float*)d_in[0];
    const float* item_w = (const float*)d_in[1];
    const int*   eidx   = (const int*)d_in[2];     // [2, N_EDGES] int32
    const float* ew     = (const float*)d_in[3];   // [N_EDGES]
    const int* src = eidx;
    const int* dst = eidx + N_EDGES;
    float* acc = (float*)d_out;

    const size_t xbytes = (size_t)N_NODES * EMB_DIM * sizeof(float);  // 128 MB
    // CSR layout after the two x buffers
    size_t off = 2 * xbytes;
    size_t rowptr_off = off;                 off += (size_t)(N_NODES + 1) * 4;
    size_t cursor_off = off;                 off += (size_t)N_NODES * 4;
    size_t csrsrc_off = off;                 off += (size_t)N_EDGES * 4;
    size_t csrw_off   = off;                 off += (size_t)N_EDGES * 4;
    size_t bsums_off  = off;                 off += 4096;
    const size_t need = off;

    const int blk = 256;
    const int grid_e = 2048;

    if (ws_size >= need) {
        float* x1 = (float*)d_ws;
        float* x2 = (float*)((char*)d_ws + xbytes);
        int*   rowptr  = (int*)((char*)d_ws + rowptr_off);
        int*   cursor  = (int*)((char*)d_ws + cursor_off);
        int*   csr_src = (int*)((char*)d_ws + csrsrc_off);
        float* csr_w   = (float*)((char*)d_ws + csrw_off);
        int*   bsums   = (int*)((char*)d_ws + bsums_off);

        const int nb_scan = (N_NODES + SCAN_ELEMS - 1) / SCAN_ELEMS;  // 489

        // --- CSR build ---
        k_zero_int<<<512, blk, 0, stream>>>(rowptr, N_NODES + 1);
        k_count<<<grid_e, blk, 0, stream>>>(dst, rowptr);
        k_scan1<<<nb_scan, 256, 0, stream>>>(rowptr, bsums);
        k_scan2<<<1, 512, 0, stream>>>(bsums, nb_scan);
        k_scan3<<<grid_e, blk, 0, stream>>>(rowptr, bsums, cursor);
        k_fill<<<grid_e, blk, 0, stream>>>(src, dst, ew, cursor, csr_src, csr_w);

        // --- layers ---
        const int grid_l = 4096;   // 16384 waves, ~31 nodes each
        k_layer1<<<grid_l, blk, 0, stream>>>(user_w, item_w, rowptr, csr_src,
                                             csr_w, x1, acc);
        k_layerN<<<grid_l, blk, 0, stream>>>(x1, rowptr, csr_src, csr_w, x2, acc);
        k_layerN<<<grid_l, blk, 0, stream>>>(x2, rowptr, csr_src, csr_w, nullptr, acc);
    } else {
        // fallback: atomic scatter path (round-1, known good)
        float* xcur = (float*)d_ws;
        float* xnext = xcur + (ll)N_NODES * EMB_DIM;
        fb_init<<<grid_e, blk, 0, stream>>>(user_w, item_w, acc, xcur);
        for (int layer = 0; layer < N_LAYERS; ++layer) {
            fb_zero<<<grid_e, blk, 0, stream>>>(xnext);
            fb_scatter<<<4096, blk, 0, stream>>>(xcur, src, dst, ew, xnext);
            fb_accadd<<<grid_e, blk, 0, stream>>>(xnext, acc);
            float* tmp = xcur; xcur = xnext; xnext = tmp;
        }
    }
}

// Round 3
// 440.995 us; speedup vs baseline: 2.4320x; 1.9384x over previous
//
#include <hip/hip_runtime.h>

#define N_USERS 100000
#define N_ITEMS 400000
#define N_NODES 500000
#define EMB_DIM 64
#define N_EDGES 1200000

typedef long long ll;
typedef float f4 __attribute__((ext_vector_type(4)));

// ---------------------------------------------------------------------------
// CSR build: counts -> 2-level exclusive scan -> fill (csr as int2{src,w})
// ---------------------------------------------------------------------------

__global__ void k_zero_int(int* __restrict__ p, int n) {
    int stride = gridDim.x * blockDim.x;
    for (int i = blockIdx.x * blockDim.x + threadIdx.x; i < n; i += stride)
        p[i] = 0;
}

__global__ void k_count(const int* __restrict__ dst, int* __restrict__ cnt) {
    int stride = gridDim.x * blockDim.x;
    for (int e = blockIdx.x * blockDim.x + threadIdx.x; e < N_EDGES; e += stride)
        atomicAdd(&cnt[dst[e]], 1);
}

#define SCAN_ELEMS 1024
__global__ void k_scan1(int* __restrict__ data, int* __restrict__ blocksums) {
    __shared__ int tmp[256];
    int b = blockIdx.x;
    int t = threadIdx.x;
    int base = b * SCAN_ELEMS + t * 4;
    int v[4];
    #pragma unroll
    for (int k = 0; k < 4; ++k) {
        int i = base + k;
        v[k] = (i < N_NODES) ? data[i] : 0;
    }
    int tsum = v[0] + v[1] + v[2] + v[3];
    tmp[t] = tsum;
    __syncthreads();
    for (int off = 1; off < 256; off <<= 1) {
        int x = (t >= off) ? tmp[t - off] : 0;
        __syncthreads();
        tmp[t] += x;
        __syncthreads();
    }
    int run = tmp[t] - tsum;
    #pragma unroll
    for (int k = 0; k < 4; ++k) {
        int i = base + k;
        if (i < N_NODES) data[i] = run;
        run += v[k];
    }
    if (t == 255) blocksums[b] = tmp[255];
}

__global__ void k_scan2(int* __restrict__ blocksums, int nb) {
    __shared__ int tmp[512];
    int t = threadIdx.x;
    int v = (t < nb) ? blocksums[t] : 0;
    tmp[t] = v;
    __syncthreads();
    for (int off = 1; off < 512; off <<= 1) {
        int x = (t >= off) ? tmp[t - off] : 0;
        __syncthreads();
        tmp[t] += x;
        __syncthreads();
    }
    if (t < nb) blocksums[t] = tmp[t] - v;
}

__global__ void k_scan3(int* __restrict__ rowptr, const int* __restrict__ blocksums,
                        int* __restrict__ cursor) {
    int stride = gridDim.x * blockDim.x;
    for (int i = blockIdx.x * blockDim.x + threadIdx.x; i < N_NODES; i += stride) {
        int v = rowptr[i] + blocksums[i >> 10];
        rowptr[i] = v;
        cursor[i] = v;
    }
    if (blockIdx.x == 0 && threadIdx.x == 0) rowptr[N_NODES] = N_EDGES;
}

__global__ void k_fill(const int* __restrict__ src, const int* __restrict__ dst,
                       const float* __restrict__ w,
                       int* __restrict__ cursor, int2* __restrict__ csr) {
    int stride = gridDim.x * blockDim.x;
    for (int e = blockIdx.x * blockDim.x + threadIdx.x; e < N_EDGES; e += stride) {
        int t = dst[e];
        int pos = atomicAdd(&cursor[t], 1);
        csr[pos] = make_int2(src[e], __float_as_int(w[e]));
    }
}

// ---------------------------------------------------------------------------
// Layer kernels: one wave serves 4 nodes (16 lanes x float4 each).
// ---------------------------------------------------------------------------

// Layer 1: gather from split tables; x1 = A x0; acc = 0.25*(x0 + x1).
__global__ void k_layer1(const f4* __restrict__ u4, const f4* __restrict__ i4,
                         const int* __restrict__ rowptr,
                         const int2* __restrict__ csr,
                         f4* __restrict__ xout, f4* __restrict__ acc) {
    int wave = (blockIdx.x * blockDim.x + threadIdx.x) >> 6;
    int lane = threadIdx.x & 63;
    int sub = lane >> 4;      // node within wave (0..3)
    int fl  = lane & 15;      // float4 slot within row
    int nwaves = (gridDim.x * blockDim.x) >> 6;
    for (int nb = wave * 4; nb < N_NODES; nb += nwaves * 4) {
        int n = nb + sub;                      // N_NODES % 4 == 0
        int start = rowptr[n];
        int end   = rowptr[n + 1];
        f4 s = {0.f, 0.f, 0.f, 0.f};
        int j = start;
        for (; j + 1 < end; j += 2) {
            int2 e0 = csr[j];
            int2 e1 = csr[j + 1];
            const f4* b0 = (e0.x < N_USERS) ? (u4 + (ll)e0.x * 16)
                                            : (i4 + (ll)(e0.x - N_USERS) * 16);
            const f4* b1 = (e1.x < N_USERS) ? (u4 + (ll)e1.x * 16)
                                            : (i4 + (ll)(e1.x - N_USERS) * 16);
            f4 v0 = b0[fl];
            f4 v1 = b1[fl];
            s += __int_as_float(e0.y) * v0;
            s += __int_as_float(e1.y) * v1;
        }
        if (j < end) {
            int2 e = csr[j];
            const f4* b = (e.x < N_USERS) ? (u4 + (ll)e.x * 16)
                                          : (i4 + (ll)(e.x - N_USERS) * 16);
            s += __int_as_float(e.y) * b[fl];
        }
        const f4* bx = (n < N_USERS) ? (u4 + (ll)n * 16)
                                     : (i4 + (ll)(n - N_USERS) * 16);
        f4 x0 = bx[fl];
        ll idx = (ll)n * 16 + fl;
        xout[idx] = s;
        __builtin_nontemporal_store(0.25f * (x0 + s), &acc[idx]);
    }
}

// Layers 2..L: x_{l+1} = A x_l; acc += 0.25*x_{l+1}; optionally write xout.
__global__ void k_layerN(const f4* __restrict__ xin,
                         const int* __restrict__ rowptr,
                         const int2* __restrict__ csr,
                         f4* __restrict__ xout,    // may be null
                         f4* __restrict__ acc) {
    int wave = (blockIdx.x * blockDim.x + threadIdx.x) >> 6;
    int lane = threadIdx.x & 63;
    int sub = lane >> 4;
    int fl  = lane & 15;
    int nwaves = (gridDim.x * blockDim.x) >> 6;
    for (int nb = wave * 4; nb < N_NODES; nb += nwaves * 4) {
        int n = nb + sub;
        int start = rowptr[n];
        int end   = rowptr[n + 1];
        f4 s = {0.f, 0.f, 0.f, 0.f};
        int j = start;
        for (; j + 1 < end; j += 2) {
            int2 e0 = csr[j];
            int2 e1 = csr[j + 1];
            f4 v0 = xin[(ll)e0.x * 16 + fl];
            f4 v1 = xin[(ll)e1.x * 16 + fl];
            s += __int_as_float(e0.y) * v0;
            s += __int_as_float(e1.y) * v1;
        }
        if (j < end) {
            int2 e = csr[j];
            s += __int_as_float(e.y) * xin[(ll)e.x * 16 + fl];
        }
        ll idx = (ll)n * 16 + fl;
        if (xout) xout[idx] = s;
        f4 a = __builtin_nontemporal_load(&acc[idx]);
        a += 0.25f * s;
        __builtin_nontemporal_store(a, &acc[idx]);
    }
}

// ---------------------------------------------------------------------------
// Fallback (round-1 atomic path) in case ws is too small for CSR arrays.
// ---------------------------------------------------------------------------

__global__ void fb_init(const float* __restrict__ user_w,
                        const float* __restrict__ item_w,
                        float* __restrict__ acc, float* __restrict__ xcur) {
    const ll total4 = (ll)N_NODES * EMB_DIM / 4;
    const ll user4 = (ll)N_USERS * EMB_DIM / 4;
    const float4* uw = (const float4*)user_w;
    const float4* iw = (const float4*)item_w;
    float4* a4 = (float4*)acc;
    float4* x4 = (float4*)xcur;
    ll stride = (ll)gridDim.x * blockDim.x;
    for (ll i = (ll)blockIdx.x * blockDim.x + threadIdx.x; i < total4; i += stride) {
        float4 v = (i < user4) ? uw[i] : iw[i - user4];
        x4[i] = v;
        a4[i] = make_float4(0.25f * v.x, 0.25f * v.y, 0.25f * v.z, 0.25f * v.w);
    }
}
__global__ void fb_zero(float* __restrict__ p) {
    const ll total4 = (ll)N_NODES * EMB_DIM / 4;
    float4* p4 = (float4*)p;
    ll stride = (ll)gridDim.x * blockDim.x;
    float4 z = make_float4(0.f, 0.f, 0.f, 0.f);
    for (ll i = (ll)blockIdx.x * blockDim.x + threadIdx.x; i < total4; i += stride)
        p4[i] = z;
}
__global__ void fb_scatter(const float* __restrict__ xcur, const int* __restrict__ src,
                           const int* __restrict__ dst, const float* __restrict__ w,
                           float* __restrict__ xnext) {
    const int gpb = blockDim.x >> 6;
    const int d = threadIdx.x & 63;
    int eg = blockIdx.x * gpb + (threadIdx.x >> 6);
    const int estride = gridDim.x * gpb;
    for (int e = eg; e < N_EDGES; e += estride) {
        int s = src[e]; int t = dst[e]; float wt = w[e];
        atomicAdd(&xnext[(ll)t * EMB_DIM + d], xcur[(ll)s * EMB_DIM + d] * wt);
    }
}
__global__ void fb_accadd(const float* __restrict__ xn, float* __restrict__ acc) {
    const ll total4 = (ll)N_NODES * EMB_DIM / 4;
    const float4* x4 = (const float4*)xn;
    float4* a4 = (float4*)acc;
    ll stride = (ll)gridDim.x * blockDim.x;
    for (ll i = (ll)blockIdx.x * blockDim.x + threadIdx.x; i < total4; i += stride) {
        float4 v = x4[i]; float4 a = a4[i];
        a.x += 0.25f * v.x; a.y += 0.25f * v.y;
        a.z += 0.25f * v.z; a.w += 0.25f * v.w;
        a4[i] = a;
    }
}

// ---------------------------------------------------------------------------

extern "C" void kernel_launch(void* const* d_in, const int* in_sizes, int n_in,
                              void* d_out, int out_size, void* d_ws, size_t ws_size,
                              hipStream_t stream) {
    const float* user_w = (const float*)d_in[0];
    const float* item_w = (const float*)d_in[1];
    const int*   eidx   = (const int*)d_in[2];     // [2, N_EDGES] int32
    const float* ew     = (const float*)d_in[3];   // [N_EDGES]
    const int* src = eidx;
    const int* dst = eidx + N_EDGES;

    const size_t xbytes = (size_t)N_NODES * EMB_DIM * sizeof(float);  // 128 MB
    size_t off = 2 * xbytes;
    size_t rowptr_off = off;                 off += (size_t)(N_NODES + 1) * 4;
    size_t cursor_off = off;                 off += (size_t)N_NODES * 4;
    size_t csr_off    = off;                 off += (size_t)N_EDGES * 8;
    size_t bsums_off  = off;                 off += 4096;
    const size_t need = off;

    const int blk = 256;
    const int grid_e = 2048;

    if (ws_size >= need) {
        f4*   x1 = (f4*)d_ws;
        f4*   x2 = (f4*)((char*)d_ws + xbytes);
        int*  rowptr = (int*)((char*)d_ws + rowptr_off);
        int*  cursor = (int*)((char*)d_ws + cursor_off);
        int2* csr    = (int2*)((char*)d_ws + csr_off);
        int*  bsums  = (int*)((char*)d_ws + bsums_off);
        f4*   acc    = (f4*)d_out;
        const f4* u4 = (const f4*)user_w;
        const f4* i4 = (const f4*)item_w;

        const int nb_scan = (N_NODES + SCAN_ELEMS - 1) / SCAN_ELEMS;  // 489

        // --- CSR build ---
        k_zero_int<<<512, blk, 0, stream>>>(rowptr, N_NODES + 1);
        k_count<<<grid_e, blk, 0, stream>>>(dst, rowptr);
        k_scan1<<<nb_scan, 256, 0, stream>>>(rowptr, bsums);
        k_scan2<<<1, 512, 0, stream>>>(bsums, nb_scan);
        k_scan3<<<grid_e, blk, 0, stream>>>(rowptr, bsums, cursor);
        k_fill<<<grid_e, blk, 0, stream>>>(src, dst, ew, cursor, csr);

        // --- layers ---
        const int grid_l = 4096;   // 16384 waves x 4 nodes = 65536 nodes/iter
        k_layer1<<<grid_l, blk, 0, stream>>>(u4, i4, rowptr, csr, x1, acc);
        k_layerN<<<grid_l, blk, 0, stream>>>(x1, rowptr, csr, x2, acc);
        k_layerN<<<grid_l, blk, 0, stream>>>(x2, rowptr, csr, nullptr, acc);
    } else {
        float* acc = (float*)d_out;
        float* xcur = (float*)d_ws;
        float* xnext = xcur + (ll)N_NODES * EMB_DIM;
        fb_init<<<grid_e, blk, 0, stream>>>(user_w, item_w, acc, xcur);
        for (int layer = 0; layer < 3; ++layer) {
            fb_zero<<<grid_e, blk, 0, stream>>>(xnext);
            fb_scatter<<<4096, blk, 0, stream>>>(xcur, src, dst, ew, xnext);
            fb_accadd<<<grid_e, blk, 0, stream>>>(xnext, acc);
            float* tmp = xcur; xcur = xnext; xnext = tmp;
        }
    }
}

// Round 4
// 410.682 us; speedup vs baseline: 2.6115x; 1.0738x over previous
//
#include <hip/hip_runtime.h>

#define N_USERS 100000
#define N_ITEMS 400000
#define N_NODES 500000
#define EMB_DIM 64
#define N_EDGES 1200000

typedef long long ll;
typedef float f4 __attribute__((ext_vector_type(4)));

// ---------------------------------------------------------------------------
// CSR build: counts -> 2-level exclusive scan -> fill (csr as int2{src,w})
// ---------------------------------------------------------------------------

__global__ void k_zero_int(int* __restrict__ p, int n) {
    int stride = gridDim.x * blockDim.x;
    for (int i = blockIdx.x * blockDim.x + threadIdx.x; i < n; i += stride)
        p[i] = 0;
}

__global__ void k_count(const int* __restrict__ dst, int* __restrict__ cnt) {
    int stride = gridDim.x * blockDim.x;
    for (int e = blockIdx.x * blockDim.x + threadIdx.x; e < N_EDGES; e += stride)
        atomicAdd(&cnt[dst[e]], 1);
}

#define SCAN_ELEMS 1024
__global__ void k_scan1(int* __restrict__ data, int* __restrict__ blocksums) {
    __shared__ int tmp[256];
    int b = blockIdx.x;
    int t = threadIdx.x;
    int base = b * SCAN_ELEMS + t * 4;
    int v[4];
    #pragma unroll
    for (int k = 0; k < 4; ++k) {
        int i = base + k;
        v[k] = (i < N_NODES) ? data[i] : 0;
    }
    int tsum = v[0] + v[1] + v[2] + v[3];
    tmp[t] = tsum;
    __syncthreads();
    for (int off = 1; off < 256; off <<= 1) {
        int x = (t >= off) ? tmp[t - off] : 0;
        __syncthreads();
        tmp[t] += x;
        __syncthreads();
    }
    int run = tmp[t] - tsum;
    #pragma unroll
    for (int k = 0; k < 4; ++k) {
        int i = base + k;
        if (i < N_NODES) data[i] = run;
        run += v[k];
    }
    if (t == 255) blocksums[b] = tmp[255];
}

__global__ void k_scan2(int* __restrict__ blocksums, int nb) {
    __shared__ int tmp[512];
    int t = threadIdx.x;
    int v = (t < nb) ? blocksums[t] : 0;
    tmp[t] = v;
    __syncthreads();
    for (int off = 1; off < 512; off <<= 1) {
        int x = (t >= off) ? tmp[t - off] : 0;
        __syncthreads();
        tmp[t] += x;
        __syncthreads();
    }
    if (t < nb) blocksums[t] = tmp[t] - v;
}

__global__ void k_scan3(int* __restrict__ rowptr, const int* __restrict__ blocksums,
                        int* __restrict__ cursor) {
    int stride = gridDim.x * blockDim.x;
    for (int i = blockIdx.x * blockDim.x + threadIdx.x; i < N_NODES; i += stride) {
        int v = rowptr[i] + blocksums[i >> 10];
        rowptr[i] = v;
        cursor[i] = v;
    }
    if (blockIdx.x == 0 && threadIdx.x == 0) rowptr[N_NODES] = N_EDGES;
}

__global__ void k_fill(const int* __restrict__ src, const int* __restrict__ dst,
                       const float* __restrict__ w,
                       int* __restrict__ cursor, int2* __restrict__ csr) {
    int stride = gridDim.x * blockDim.x;
    for (int e = blockIdx.x * blockDim.x + threadIdx.x; e < N_EDGES; e += stride) {
        int t = dst[e];
        int pos = atomicAdd(&cursor[t], 1);
        csr[pos] = make_int2(src[e], __float_as_int(w[e]));
    }
}

// ---------------------------------------------------------------------------
// Propagation: one wave = 4 nodes (16 lanes x float4 each).
// Batch-of-4 predicated gathers (clamped to last edge -> duplicate addrs are
// cache hits), remainder loop for deg > 4 (9% of nodes).
// ---------------------------------------------------------------------------

__device__ __forceinline__ const f4* tab_row(const f4* u4, const f4* i4, int s) {
    return (s < N_USERS) ? (u4 + (ll)s * 16) : (i4 + (ll)(s - N_USERS) * 16);
}

template <bool FIRST>
__global__ void k_prop(const f4* __restrict__ u4, const f4* __restrict__ i4,
                       const f4* __restrict__ xin,
                       const int* __restrict__ rowptr,
                       const int2* __restrict__ csr,
                       f4* __restrict__ xout) {
    int wave = (blockIdx.x * blockDim.x + threadIdx.x) >> 6;
    int lane = threadIdx.x & 63;
    int sub = lane >> 4;
    int fl  = lane & 15;
    int nwaves = (gridDim.x * blockDim.x) >> 6;
    for (int nb = wave * 4; nb < N_NODES; nb += nwaves * 4) {
        int n = nb + sub;
        int start = rowptr[n];
        int end   = rowptr[n + 1];
        int deg = end - start;
        f4 s = {0.f, 0.f, 0.f, 0.f};
        if (deg > 0) {
            int lastj = end - 1;
            int j1 = start + 1 < end ? start + 1 : lastj;
            int j2 = start + 2 < end ? start + 2 : lastj;
            int j3 = start + 3 < end ? start + 3 : lastj;
            int2 e0 = csr[start];
            int2 e1 = csr[j1];
            int2 e2 = csr[j2];
            int2 e3 = csr[j3];
            float w0 = __int_as_float(e0.y);
            float w1 = (deg > 1) ? __int_as_float(e1.y) : 0.f;
            float w2 = (deg > 2) ? __int_as_float(e2.y) : 0.f;
            float w3 = (deg > 3) ? __int_as_float(e3.y) : 0.f;
            f4 v0, v1, v2, v3;
            if (FIRST) {
                v0 = tab_row(u4, i4, e0.x)[fl];
                v1 = tab_row(u4, i4, e1.x)[fl];
                v2 = tab_row(u4, i4, e2.x)[fl];
                v3 = tab_row(u4, i4, e3.x)[fl];
            } else {
                v0 = xin[(ll)e0.x * 16 + fl];
                v1 = xin[(ll)e1.x * 16 + fl];
                v2 = xin[(ll)e2.x * 16 + fl];
                v3 = xin[(ll)e3.x * 16 + fl];
            }
            s = w0 * v0 + w1 * v1 + w2 * v2 + w3 * v3;
            // remainder (deg > 4)
            int j = start + 4;
            for (; j + 1 < end; j += 2) {
                int2 a = csr[j];
                int2 b = csr[j + 1];
                f4 va = FIRST ? tab_row(u4, i4, a.x)[fl] : xin[(ll)a.x * 16 + fl];
                f4 vb = FIRST ? tab_row(u4, i4, b.x)[fl] : xin[(ll)b.x * 16 + fl];
                s += __int_as_float(a.y) * va;
                s += __int_as_float(b.y) * vb;
            }
            if (j < end) {
                int2 a = csr[j];
                f4 va = FIRST ? tab_row(u4, i4, a.x)[fl] : xin[(ll)a.x * 16 + fl];
                s += __int_as_float(a.y) * va;
            }
        }
        xout[(ll)n * 16 + fl] = s;
    }
}

// Final layer: gathers x3 from x2, then acc = 0.25*(x0 + x1 + x2 + x3).
// x0/x1 are single-use streams -> non-temporal so they don't evict the
// gather-hot x2 from L3. x2[n] coalesced read is an L3 hit.
__global__ void k_final(const f4* __restrict__ u4, const f4* __restrict__ i4,
                        const f4* __restrict__ x1, const f4* __restrict__ x2,
                        const int* __restrict__ rowptr,
                        const int2* __restrict__ csr,
                        f4* __restrict__ acc) {
    int wave = (blockIdx.x * blockDim.x + threadIdx.x) >> 6;
    int lane = threadIdx.x & 63;
    int sub = lane >> 4;
    int fl  = lane & 15;
    int nwaves = (gridDim.x * blockDim.x) >> 6;
    for (int nb = wave * 4; nb < N_NODES; nb += nwaves * 4) {
        int n = nb + sub;
        int start = rowptr[n];
        int end   = rowptr[n + 1];
        int deg = end - start;
        f4 s = {0.f, 0.f, 0.f, 0.f};
        if (deg > 0) {
            int lastj = end - 1;
            int j1 = start + 1 < end ? start + 1 : lastj;
            int j2 = start + 2 < end ? start + 2 : lastj;
            int j3 = start + 3 < end ? start + 3 : lastj;
            int2 e0 = csr[start];
            int2 e1 = csr[j1];
            int2 e2 = csr[j2];
            int2 e3 = csr[j3];
            float w0 = __int_as_float(e0.y);
            float w1 = (deg > 1) ? __int_as_float(e1.y) : 0.f;
            float w2 = (deg > 2) ? __int_as_float(e2.y) : 0.f;
            float w3 = (deg > 3) ? __int_as_float(e3.y) : 0.f;
            f4 v0 = x2[(ll)e0.x * 16 + fl];
            f4 v1 = x2[(ll)e1.x * 16 + fl];
            f4 v2 = x2[(ll)e2.x * 16 + fl];
            f4 v3 = x2[(ll)e3.x * 16 + fl];
            s = w0 * v0 + w1 * v1 + w2 * v2 + w3 * v3;
            int j = start + 4;
            for (; j + 1 < end; j += 2) {
                int2 a = csr[j];
                int2 b = csr[j + 1];
                f4 va = x2[(ll)a.x * 16 + fl];
                f4 vb = x2[(ll)b.x * 16 + fl];
                s += __int_as_float(a.y) * va;
                s += __int_as_float(b.y) * vb;
            }
            if (j < end) {
                int2 a = csr[j];
                s += __int_as_float(a.y) * x2[(ll)a.x * 16 + fl];
            }
        }
        ll idx = (ll)n * 16 + fl;
        f4 x0v = __builtin_nontemporal_load(&tab_row(u4, i4, n)[fl]);
        f4 x1v = __builtin_nontemporal_load(&x1[idx]);
        f4 x2v = x2[idx];
        __builtin_nontemporal_store(0.25f * (x0v + x1v + x2v + s), &acc[idx]);
    }
}

// ---------------------------------------------------------------------------
// Fallback (round-1 atomic path) in case ws is too small for CSR arrays.
// ---------------------------------------------------------------------------

__global__ void fb_init(const float* __restrict__ user_w,
                        const float* __restrict__ item_w,
                        float* __restrict__ acc, float* __restrict__ xcur) {
    const ll total4 = (ll)N_NODES * EMB_DIM / 4;
    const ll user4 = (ll)N_USERS * EMB_DIM / 4;
    const float4* uw = (const float4*)user_w;
    const float4* iw = (const float4*)item_w;
    float4* a4 = (float4*)acc;
    float4* x4 = (float4*)xcur;
    ll stride = (ll)gridDim.x * blockDim.x;
    for (ll i = (ll)blockIdx.x * blockDim.x + threadIdx.x; i < total4; i += stride) {
        float4 v = (i < user4) ? uw[i] : iw[i - user4];
        x4[i] = v;
        a4[i] = make_float4(0.25f * v.x, 0.25f * v.y, 0.25f * v.z, 0.25f * v.w);
    }
}
__global__ void fb_zero(float* __restrict__ p) {
    const ll total4 = (ll)N_NODES * EMB_DIM / 4;
    float4* p4 = (float4*)p;
    ll stride = (ll)gridDim.x * blockDim.x;
    float4 z = make_float4(0.f, 0.f, 0.f, 0.f);
    for (ll i = (ll)blockIdx.x * blockDim.x + threadIdx.x; i < total4; i += stride)
        p4[i] = z;
}
__global__ void fb_scatter(const float* __restrict__ xcur, const int* __restrict__ src,
                           const int* __restrict__ dst, const float* __restrict__ w,
                           float* __restrict__ xnext) {
    const int gpb = blockDim.x >> 6;
    const int d = threadIdx.x & 63;
    int eg = blockIdx.x * gpb + (threadIdx.x >> 6);
    const int estride = gridDim.x * gpb;
    for (int e = eg; e < N_EDGES; e += estride) {
        int s = src[e]; int t = dst[e]; float wt = w[e];
        atomicAdd(&xnext[(ll)t * EMB_DIM + d], xcur[(ll)s * EMB_DIM + d] * wt);
    }
}
__global__ void fb_accadd(const float* __restrict__ xn, float* __restrict__ acc) {
    const ll total4 = (ll)N_NODES * EMB_DIM / 4;
    const float4* x4 = (const float4*)xn;
    float4* a4 = (float4*)acc;
    ll stride = (ll)gridDim.x * blockDim.x;
    for (ll i = (ll)blockIdx.x * blockDim.x + threadIdx.x; i < total4; i += stride) {
        float4 v = x4[i]; float4 a = a4[i];
        a.x += 0.25f * v.x; a.y += 0.25f * v.y;
        a.z += 0.25f * v.z; a.w += 0.25f * v.w;
        a4[i] = a;
    }
}

// ---------------------------------------------------------------------------

extern "C" void kernel_launch(void* const* d_in, const int* in_sizes, int n_in,
                              void* d_out, int out_size, void* d_ws, size_t ws_size,
                              hipStream_t stream) {
    const float* user_w = (const float*)d_in[0];
    const float* item_w = (const float*)d_in[1];
    const int*   eidx   = (const int*)d_in[2];     // [2, N_EDGES] int32
    const float* ew     = (const float*)d_in[3];   // [N_EDGES]
    const int* src = eidx;
    const int* dst = eidx + N_EDGES;

    const size_t xbytes = (size_t)N_NODES * EMB_DIM * sizeof(float);  // 128 MB
    size_t off = 2 * xbytes;
    size_t rowptr_off = off;                 off += (size_t)(N_NODES + 1) * 4;
    size_t cursor_off = off;                 off += (size_t)N_NODES * 4;
    size_t csr_off    = off;                 off += (size_t)N_EDGES * 8;
    size_t bsums_off  = off;                 off += 4096;
    const size_t need = off;

    const int blk = 256;
    const int grid_e = 2048;

    if (ws_size >= need) {
        f4*   x1 = (f4*)d_ws;
        f4*   x2 = (f4*)((char*)d_ws + xbytes);
        int*  rowptr = (int*)((char*)d_ws + rowptr_off);
        int*  cursor = (int*)((char*)d_ws + cursor_off);
        int2* csr    = (int2*)((char*)d_ws + csr_off);
        int*  bsums  = (int*)((char*)d_ws + bsums_off);
        f4*   acc    = (f4*)d_out;
        const f4* u4 = (const f4*)user_w;
        const f4* i4 = (const f4*)item_w;

        const int nb_scan = (N_NODES + SCAN_ELEMS - 1) / SCAN_ELEMS;  // 489

        // --- CSR build ---
        k_zero_int<<<512, blk, 0, stream>>>(rowptr, N_NODES + 1);
        k_count<<<grid_e, blk, 0, stream>>>(dst, rowptr);
        k_scan1<<<nb_scan, 256, 0, stream>>>(rowptr, bsums);
        k_scan2<<<1, 512, 0, stream>>>(bsums, nb_scan);
        k_scan3<<<grid_e, blk, 0, stream>>>(rowptr, bsums, cursor);
        k_fill<<<grid_e, blk, 0, stream>>>(src, dst, ew, cursor, csr);

        // --- layers (no acc RMW: final pass composes the mean) ---
        const int grid_l = 4096;
        k_prop<true><<<grid_l, blk, 0, stream>>>(u4, i4, nullptr, rowptr, csr, x1);
        k_prop<false><<<grid_l, blk, 0, stream>>>(u4, i4, x1, rowptr, csr, x2);
        k_final<<<grid_l, blk, 0, stream>>>(u4, i4, x1, x2, rowptr, csr, acc);
    } else {
        float* acc = (float*)d_out;
        float* xcur = (float*)d_ws;
        float* xnext = xcur + (ll)N_NODES * EMB_DIM;
        fb_init<<<grid_e, blk, 0, stream>>>(user_w, item_w, acc, xcur);
        for (int layer = 0; layer < 3; ++layer) {
            fb_zero<<<grid_e, blk, 0, stream>>>(xnext);
            fb_scatter<<<4096, blk, 0, stream>>>(xcur, src, dst, ew, xnext);
            fb_accadd<<<grid_e, blk, 0, stream>>>(xnext, acc);
            float* tmp = xcur; xcur = xnext; xnext = tmp;
        }
    }
}

// Round 5
// 343.319 us; speedup vs baseline: 3.1239x; 1.1962x over previous
//
#include <hip/hip_runtime.h>

#define N_USERS 100000
#define N_ITEMS 400000
#define N_NODES 500000
#define EMB_DIM 64
#define N_EDGES 1200000

typedef long long ll;
typedef float f4 __attribute__((ext_vector_type(4)));
typedef float f8 __attribute__((ext_vector_type(8)));
typedef unsigned short u16;
typedef u16 us4 __attribute__((ext_vector_type(4)));   // 8 B  (4 bf16)
typedef u16 us8 __attribute__((ext_vector_type(8)));   // 16 B (8 bf16)

__device__ __forceinline__ u16 f2bf(float f) {
    unsigned u = __float_as_uint(f);
    u += 0x7FFF + ((u >> 16) & 1);          // round-to-nearest-even
    return (u16)(u >> 16);
}
__device__ __forceinline__ float bf2f(u16 h) {
    return __uint_as_float(((unsigned)h) << 16);
}
__device__ __forceinline__ void fma8(f8& s, float w, us8 v) {
    #pragma unroll
    for (int k = 0; k < 8; ++k) s[k] += w * bf2f(v[k]);
}

// ---------------------------------------------------------------------------
// CSR build: counts -> 2-level exclusive scan -> fill (csr as int2{src,w})
// ---------------------------------------------------------------------------

__global__ void k_zero_int(int* __restrict__ p, int n) {
    int stride = gridDim.x * blockDim.x;
    for (int i = blockIdx.x * blockDim.x + threadIdx.x; i < n; i += stride)
        p[i] = 0;
}

__global__ void k_count(const int* __restrict__ dst, int* __restrict__ cnt) {
    int stride = gridDim.x * blockDim.x;
    for (int e = blockIdx.x * blockDim.x + threadIdx.x; e < N_EDGES; e += stride)
        atomicAdd(&cnt[dst[e]], 1);
}

#define SCAN_ELEMS 1024
__global__ void k_scan1(int* __restrict__ data, int* __restrict__ blocksums) {
    __shared__ int tmp[256];
    int b = blockIdx.x;
    int t = threadIdx.x;
    int base = b * SCAN_ELEMS + t * 4;
    int v[4];
    #pragma unroll
    for (int k = 0; k < 4; ++k) {
        int i = base + k;
        v[k] = (i < N_NODES) ? data[i] : 0;
    }
    int tsum = v[0] + v[1] + v[2] + v[3];
    tmp[t] = tsum;
    __syncthreads();
    for (int off = 1; off < 256; off <<= 1) {
        int x = (t >= off) ? tmp[t - off] : 0;
        __syncthreads();
        tmp[t] += x;
        __syncthreads();
    }
    int run = tmp[t] - tsum;
    #pragma unroll
    for (int k = 0; k < 4; ++k) {
        int i = base + k;
        if (i < N_NODES) data[i] = run;
        run += v[k];
    }
    if (t == 255) blocksums[b] = tmp[255];
}

__global__ void k_scan2(int* __restrict__ blocksums, int nb) {
    __shared__ int tmp[512];
    int t = threadIdx.x;
    int v = (t < nb) ? blocksums[t] : 0;
    tmp[t] = v;
    __syncthreads();
    for (int off = 1; off < 512; off <<= 1) {
        int x = (t >= off) ? tmp[t - off] : 0;
        __syncthreads();
        tmp[t] += x;
        __syncthreads();
    }
    if (t < nb) blocksums[t] = tmp[t] - v;
}

__global__ void k_scan3(int* __restrict__ rowptr, const int* __restrict__ blocksums,
                        int* __restrict__ cursor) {
    int stride = gridDim.x * blockDim.x;
    for (int i = blockIdx.x * blockDim.x + threadIdx.x; i < N_NODES; i += stride) {
        int v = rowptr[i] + blocksums[i >> 10];
        rowptr[i] = v;
        cursor[i] = v;
    }
    if (blockIdx.x == 0 && threadIdx.x == 0) rowptr[N_NODES] = N_EDGES;
}

__global__ void k_fill(const int* __restrict__ src, const int* __restrict__ dst,
                       const float* __restrict__ w,
                       int* __restrict__ cursor, int2* __restrict__ csr) {
    int stride = gridDim.x * blockDim.x;
    for (int e = blockIdx.x * blockDim.x + threadIdx.x; e < N_EDGES; e += stride) {
        int t = dst[e];
        int pos = atomicAdd(&cursor[t], 1);
        csr[pos] = make_int2(src[e], __float_as_int(w[e]));
    }
}

// ---------------------------------------------------------------------------
// Propagation kernels.
// ---------------------------------------------------------------------------

__device__ __forceinline__ const f4* tab_row(const f4* u4, const f4* i4, int s) {
    return (s < N_USERS) ? (u4 + (ll)s * 16) : (i4 + (ll)(s - N_USERS) * 16);
}

// Layer 1: 4 nodes/wave, 16 lanes x f4 each; gathers fp32 tables (256 B rows);
// writes x1 as bf16 (us4 per lane, 128 B rows).
__global__ void k_prop1(const f4* __restrict__ u4, const f4* __restrict__ i4,
                        const int* __restrict__ rowptr,
                        const int2* __restrict__ csr,
                        us4* __restrict__ x1b) {
    int wave = (blockIdx.x * blockDim.x + threadIdx.x) >> 6;
    int lane = threadIdx.x & 63;
    int sub = lane >> 4;
    int fl  = lane & 15;
    int nwaves = (gridDim.x * blockDim.x) >> 6;
    for (int nb = wave * 4; nb < N_NODES; nb += nwaves * 4) {
        int n = nb + sub;
        int start = rowptr[n];
        int end   = rowptr[n + 1];
        int deg = end - start;
        f4 s = {0.f, 0.f, 0.f, 0.f};
        if (deg > 0) {
            int lastj = end - 1;
            int j1 = start + 1 < end ? start + 1 : lastj;
            int j2 = start + 2 < end ? start + 2 : lastj;
            int j3 = start + 3 < end ? start + 3 : lastj;
            int2 e0 = csr[start];
            int2 e1 = csr[j1];
            int2 e2 = csr[j2];
            int2 e3 = csr[j3];
            float w0 = __int_as_float(e0.y);
            float w1 = (deg > 1) ? __int_as_float(e1.y) : 0.f;
            float w2 = (deg > 2) ? __int_as_float(e2.y) : 0.f;
            float w3 = (deg > 3) ? __int_as_float(e3.y) : 0.f;
            f4 v0 = tab_row(u4, i4, e0.x)[fl];
            f4 v1 = tab_row(u4, i4, e1.x)[fl];
            f4 v2 = tab_row(u4, i4, e2.x)[fl];
            f4 v3 = tab_row(u4, i4, e3.x)[fl];
            s = w0 * v0 + w1 * v1 + w2 * v2 + w3 * v3;
            int j = start + 4;
            for (; j + 1 < end; j += 2) {
                int2 a = csr[j];
                int2 b = csr[j + 1];
                f4 va = tab_row(u4, i4, a.x)[fl];
                f4 vb = tab_row(u4, i4, b.x)[fl];
                s += __int_as_float(a.y) * va;
                s += __int_as_float(b.y) * vb;
            }
            if (j < end) {
                int2 a = csr[j];
                s += __int_as_float(a.y) * tab_row(u4, i4, a.x)[fl];
            }
        }
        us4 o;
        #pragma unroll
        for (int k = 0; k < 4; ++k) o[k] = f2bf(s[k]);
        x1b[(ll)n * 16 + fl] = o;    // wave-contiguous: nb*16 + lane
    }
}

// Layer 2: 8 nodes/wave, 8 lanes x bf16x8 each; gathers bf16 x1 (128 B rows,
// one 16 B load per lane); writes x2 as bf16.
__global__ void k_prop2(const us8* __restrict__ x1b,
                        const int* __restrict__ rowptr,
                        const int2* __restrict__ csr,
                        us8* __restrict__ x2b) {
    int wave = (blockIdx.x * blockDim.x + threadIdx.x) >> 6;
    int lane = threadIdx.x & 63;
    int sub = lane >> 3;      // node within wave (0..7)
    int fl  = lane & 7;       // us8 slot within row
    int nwaves = (gridDim.x * blockDim.x) >> 6;
    for (int nb = wave * 8; nb < N_NODES; nb += nwaves * 8) {
        int n = nb + sub;                       // N_NODES % 8 == 0
        int start = rowptr[n];
        int end   = rowptr[n + 1];
        int deg = end - start;
        f8 s = {0.f, 0.f, 0.f, 0.f, 0.f, 0.f, 0.f, 0.f};
        if (deg > 0) {
            int lastj = end - 1;
            int j1 = start + 1 < end ? start + 1 : lastj;
            int j2 = start + 2 < end ? start + 2 : lastj;
            int j3 = start + 3 < end ? start + 3 : lastj;
            int2 e0 = csr[start];
            int2 e1 = csr[j1];
            int2 e2 = csr[j2];
            int2 e3 = csr[j3];
            float w0 = __int_as_float(e0.y);
            float w1 = (deg > 1) ? __int_as_float(e1.y) : 0.f;
            float w2 = (deg > 2) ? __int_as_float(e2.y) : 0.f;
            float w3 = (deg > 3) ? __int_as_float(e3.y) : 0.f;
            us8 v0 = x1b[(ll)e0.x * 8 + fl];
            us8 v1 = x1b[(ll)e1.x * 8 + fl];
            us8 v2 = x1b[(ll)e2.x * 8 + fl];
            us8 v3 = x1b[(ll)e3.x * 8 + fl];
            fma8(s, w0, v0);
            fma8(s, w1, v1);
            fma8(s, w2, v2);
            fma8(s, w3, v3);
            int j = start + 4;
            for (; j + 1 < end; j += 2) {
                int2 a = csr[j];
                int2 b = csr[j + 1];
                us8 va = x1b[(ll)a.x * 8 + fl];
                us8 vb = x1b[(ll)b.x * 8 + fl];
                fma8(s, __int_as_float(a.y), va);
                fma8(s, __int_as_float(b.y), vb);
            }
            if (j < end) {
                int2 a = csr[j];
                us8 va = x1b[(ll)a.x * 8 + fl];
                fma8(s, __int_as_float(a.y), va);
            }
        }
        us8 o;
        #pragma unroll
        for (int k = 0; k < 8; ++k) o[k] = f2bf(s[k]);
        x2b[(ll)n * 8 + fl] = o;     // wave-contiguous: nb*8 + lane
    }
}

// Final: gathers x3 from bf16 x2; acc = 0.25*(x0 + x1 + x2 + x3) in fp32.
// x0/x1 are single-use streams -> non-temporal.
__global__ void k_final(const f4* __restrict__ u4, const f4* __restrict__ i4,
                        const us8* __restrict__ x1b, const us8* __restrict__ x2b,
                        const int* __restrict__ rowptr,
                        const int2* __restrict__ csr,
                        f4* __restrict__ acc) {
    int wave = (blockIdx.x * blockDim.x + threadIdx.x) >> 6;
    int lane = threadIdx.x & 63;
    int sub = lane >> 3;
    int fl  = lane & 7;
    int nwaves = (gridDim.x * blockDim.x) >> 6;
    for (int nb = wave * 8; nb < N_NODES; nb += nwaves * 8) {
        int n = nb + sub;
        int start = rowptr[n];
        int end   = rowptr[n + 1];
        int deg = end - start;
        f8 s = {0.f, 0.f, 0.f, 0.f, 0.f, 0.f, 0.f, 0.f};
        if (deg > 0) {
            int lastj = end - 1;
            int j1 = start + 1 < end ? start + 1 : lastj;
            int j2 = start + 2 < end ? start + 2 : lastj;
            int j3 = start + 3 < end ? start + 3 : lastj;
            int2 e0 = csr[start];
            int2 e1 = csr[j1];
            int2 e2 = csr[j2];
            int2 e3 = csr[j3];
            float w0 = __int_as_float(e0.y);
            float w1 = (deg > 1) ? __int_as_float(e1.y) : 0.f;
            float w2 = (deg > 2) ? __int_as_float(e2.y) : 0.f;
            float w3 = (deg > 3) ? __int_as_float(e3.y) : 0.f;
            us8 v0 = x2b[(ll)e0.x * 8 + fl];
            us8 v1 = x2b[(ll)e1.x * 8 + fl];
            us8 v2 = x2b[(ll)e2.x * 8 + fl];
            us8 v3 = x2b[(ll)e3.x * 8 + fl];
            fma8(s, w0, v0);
            fma8(s, w1, v1);
            fma8(s, w2, v2);
            fma8(s, w3, v3);
            int j = start + 4;
            for (; j + 1 < end; j += 2) {
                int2 a = csr[j];
                int2 b = csr[j + 1];
                us8 va = x2b[(ll)a.x * 8 + fl];
                us8 vb = x2b[(ll)b.x * 8 + fl];
                fma8(s, __int_as_float(a.y), va);
                fma8(s, __int_as_float(b.y), vb);
            }
            if (j < end) {
                int2 a = csr[j];
                us8 va = x2b[(ll)a.x * 8 + fl];
                fma8(s, __int_as_float(a.y), va);
            }
        }
        // combine: acc = 0.25*(x0 + x1 + x2 + x3)
        const f4* trow = tab_row(u4, i4, n);
        f4 x0lo = __builtin_nontemporal_load(&trow[fl * 2]);
        f4 x0hi = __builtin_nontemporal_load(&trow[fl * 2 + 1]);
        ll idx8 = (ll)n * 8 + fl;
        us8 x1v = __builtin_nontemporal_load(&x1b[idx8]);
        us8 x2v = x2b[idx8];
        f4 rlo, rhi;
        #pragma unroll
        for (int k = 0; k < 4; ++k)
            rlo[k] = 0.25f * (x0lo[k] + bf2f(x1v[k]) + bf2f(x2v[k]) + s[k]);
        #pragma unroll
        for (int k = 0; k < 4; ++k)
            rhi[k] = 0.25f * (x0hi[k] + bf2f(x1v[k + 4]) + bf2f(x2v[k + 4]) + s[k + 4]);
        f4* arow = acc + (ll)n * 16;
        __builtin_nontemporal_store(rlo, &arow[fl * 2]);
        __builtin_nontemporal_store(rhi, &arow[fl * 2 + 1]);
    }
}

// ---------------------------------------------------------------------------
// Fallback (round-1 atomic path) in case ws is too small for CSR arrays.
// ---------------------------------------------------------------------------

__global__ void fb_init(const float* __restrict__ user_w,
                        const float* __restrict__ item_w,
                        float* __restrict__ acc, float* __restrict__ xcur) {
    const ll total4 = (ll)N_NODES * EMB_DIM / 4;
    const ll user4 = (ll)N_USERS * EMB_DIM / 4;
    const float4* uw = (const float4*)user_w;
    const float4* iw = (const float4*)item_w;
    float4* a4 = (float4*)acc;
    float4* x4 = (float4*)xcur;
    ll stride = (ll)gridDim.x * blockDim.x;
    for (ll i = (ll)blockIdx.x * blockDim.x + threadIdx.x; i < total4; i += stride) {
        float4 v = (i < user4) ? uw[i] : iw[i - user4];
        x4[i] = v;
        a4[i] = make_float4(0.25f * v.x, 0.25f * v.y, 0.25f * v.z, 0.25f * v.w);
    }
}
__global__ void fb_zero(float* __restrict__ p) {
    const ll total4 = (ll)N_NODES * EMB_DIM / 4;
    float4* p4 = (float4*)p;
    ll stride = (ll)gridDim.x * blockDim.x;
    float4 z = make_float4(0.f, 0.f, 0.f, 0.f);
    for (ll i = (ll)blockIdx.x * blockDim.x + threadIdx.x; i < total4; i += stride)
        p4[i] = z;
}
__global__ void fb_scatter(const float* __restrict__ xcur, const int* __restrict__ src,
                           const int* __restrict__ dst, const float* __restrict__ w,
                           float* __restrict__ xnext) {
    const int gpb = blockDim.x >> 6;
    const int d = threadIdx.x & 63;
    int eg = blockIdx.x * gpb + (threadIdx.x >> 6);
    const int estride = gridDim.x * gpb;
    for (int e = eg; e < N_EDGES; e += estride) {
        int s = src[e]; int t = dst[e]; float wt = w[e];
        atomicAdd(&xnext[(ll)t * EMB_DIM + d], xcur[(ll)s * EMB_DIM + d] * wt);
    }
}
__global__ void fb_accadd(const float* __restrict__ xn, float* __restrict__ acc) {
    const ll total4 = (ll)N_NODES * EMB_DIM / 4;
    const float4* x4 = (const float4*)xn;
    float4* a4 = (float4*)acc;
    ll stride = (ll)gridDim.x * blockDim.x;
    for (ll i = (ll)blockIdx.x * blockDim.x + threadIdx.x; i < total4; i += stride) {
        float4 v = x4[i]; float4 a = a4[i];
        a.x += 0.25f * v.x; a.y += 0.25f * v.y;
        a.z += 0.25f * v.z; a.w += 0.25f * v.w;
        a4[i] = a;
    }
}

// ---------------------------------------------------------------------------

extern "C" void kernel_launch(void* const* d_in, const int* in_sizes, int n_in,
                              void* d_out, int out_size, void* d_ws, size_t ws_size,
                              hipStream_t stream) {
    const float* user_w = (const float*)d_in[0];
    const float* item_w = (const float*)d_in[1];
    const int*   eidx   = (const int*)d_in[2];     // [2, N_EDGES] int32
    const float* ew     = (const float*)d_in[3];   // [N_EDGES]
    const int* src = eidx;
    const int* dst = eidx + N_EDGES;

    const size_t xb_bf = (size_t)N_NODES * EMB_DIM * 2;   // 64 MB (bf16)
    size_t off = 2 * xb_bf;
    size_t rowptr_off = off;                 off += (size_t)(N_NODES + 1) * 4;
    size_t cursor_off = off;                 off += (size_t)N_NODES * 4;
    size_t csr_off    = off;                 off += (size_t)N_EDGES * 8;
    size_t bsums_off  = off;                 off += 4096;
    const size_t need = off;

    const int blk = 256;
    const int grid_e = 2048;

    if (ws_size >= need) {
        us4*  x1b4 = (us4*)d_ws;
        us8*  x1b  = (us8*)d_ws;
        us8*  x2b  = (us8*)((char*)d_ws + xb_bf);
        int*  rowptr = (int*)((char*)d_ws + rowptr_off);
        int*  cursor = (int*)((char*)d_ws + cursor_off);
        int2* csr    = (int2*)((char*)d_ws + csr_off);
        int*  bsums  = (int*)((char*)d_ws + bsums_off);
        f4*   acc    = (f4*)d_out;
        const f4* u4 = (const f4*)user_w;
        const f4* i4 = (const f4*)item_w;

        const int nb_scan = (N_NODES + SCAN_ELEMS - 1) / SCAN_ELEMS;  // 489

        // --- CSR build ---
        k_zero_int<<<512, blk, 0, stream>>>(rowptr, N_NODES + 1);
        k_count<<<grid_e, blk, 0, stream>>>(dst, rowptr);
        k_scan1<<<nb_scan, 256, 0, stream>>>(rowptr, bsums);
        k_scan2<<<1, 512, 0, stream>>>(bsums, nb_scan);
        k_scan3<<<grid_e, blk, 0, stream>>>(rowptr, bsums, cursor);
        k_fill<<<grid_e, blk, 0, stream>>>(src, dst, ew, cursor, csr);

        // --- layers ---
        const int grid_l = 4096;
        k_prop1<<<grid_l, blk, 0, stream>>>(u4, i4, rowptr, csr, x1b4);
        k_prop2<<<grid_l, blk, 0, stream>>>(x1b, rowptr, csr, x2b);
        k_final<<<grid_l, blk, 0, stream>>>(u4, i4, x1b, x2b, rowptr, csr, acc);
    } else {
        float* acc = (float*)d_out;
        float* xcur = (float*)d_ws;
        float* xnext = xcur + (ll)N_NODES * EMB_DIM;
        fb_init<<<grid_e, blk, 0, stream>>>(user_w, item_w, acc, xcur);
        for (int layer = 0; layer < 3; ++layer) {
            fb_zero<<<grid_e, blk, 0, stream>>>(xnext);
            fb_scatter<<<4096, blk, 0, stream>>>(xcur, src, dst, ew, xnext);
            fb_accadd<<<grid_e, blk, 0, stream>>>(xnext, acc);
            float* tmp = xcur; xcur = xnext; xnext = tmp;
        }
    }
}

// Round 6
// 258.188 us; speedup vs baseline: 4.1540x; 1.3297x over previous
//
#include <hip/hip_runtime.h>

#define N_USERS 100000
#define N_ITEMS 400000
#define N_NODES 500000
#define EMB_DIM 64
#define N_EDGES 1200000

#define BUCK_SHIFT 11
#define BUCK_NODES 2048                      // nodes per bucket
#define NBUCK 245                            // ceil(500000/2048)
#define BUCK_CAP 6144                        // >= max bucket count (mean 4898, +17 sigma)
#define CHUNK 4096                           // edges per k_bsort block

typedef long long ll;
typedef float f4 __attribute__((ext_vector_type(4)));
typedef float f8 __attribute__((ext_vector_type(8)));
typedef unsigned short u16;
typedef u16 us4 __attribute__((ext_vector_type(4)));   // 8 B  (4 bf16)
typedef u16 us8 __attribute__((ext_vector_type(8)));   // 16 B (8 bf16)

__device__ __forceinline__ u16 f2bf(float f) {
    unsigned u = __float_as_uint(f);
    u += 0x7FFF + ((u >> 16) & 1);          // round-to-nearest-even
    return (u16)(u >> 16);
}
__device__ __forceinline__ float bf2f(u16 h) {
    return __uint_as_float(((unsigned)h) << 16);
}
__device__ __forceinline__ void fma8(f8& s, float w, us8 v) {
    #pragma unroll
    for (int k = 0; k < 8; ++k) s[k] += w * bf2f(v[k]);
}

// ---------------------------------------------------------------------------
// CSR build, locality-staged:
//   k_init     : zero bucket cursors
//   k_bsort    : bin edges into fixed-capacity bucket regions (runs of ~16
//                entries -> near-full-line writebacks through L2)
//   k_ncount   : per-bucket LDS histogram -> coalesced per-node counts
//   k_scan1/2/3: exclusive scan of counts -> rowptr
//   k_place    : per-bucket scatter into CSR region (single-block L2 locality)
// ---------------------------------------------------------------------------

__global__ void k_init(int* __restrict__ gcur) {
    if (threadIdx.x < 256) gcur[threadIdx.x] = 0;
}

__global__ void k_bsort(const int* __restrict__ src, const int* __restrict__ dst,
                        const float* __restrict__ w,
                        int* __restrict__ gcur, uint2* __restrict__ stage) {
    __shared__ int lhist[256];
    __shared__ int gbase_s[256];
    __shared__ int lcur[256];
    int tid = threadIdx.x;
    lhist[tid] = 0;
    __syncthreads();
    int c0 = blockIdx.x * CHUNK;
    int c1 = c0 + CHUNK < N_EDGES ? c0 + CHUNK : N_EDGES;
    // pass A: histogram
    #pragma unroll
    for (int r = 0; r < CHUNK / 256; ++r) {
        int e = c0 + r * 256 + tid;
        if (e < c1) atomicAdd(&lhist[dst[e] >> BUCK_SHIFT], 1);
    }
    __syncthreads();
    if (tid < NBUCK) {
        gbase_s[tid] = atomicAdd(&gcur[tid], lhist[tid]);
        lcur[tid] = 0;
    }
    __syncthreads();
    // pass B: place into bucket regions
    #pragma unroll
    for (int r = 0; r < CHUNK / 256; ++r) {
        int e = c0 + r * 256 + tid;
        if (e < c1) {
            int s = src[e];
            int d = dst[e];
            float wt = w[e];
            int b = d >> BUCK_SHIFT;
            int k = atomicAdd(&lcur[b], 1);
            ll idx = (ll)b * BUCK_CAP + gbase_s[b] + k;
            stage[idx] = make_uint2((unsigned)s | ((unsigned)(d & (BUCK_NODES - 1)) << 19),
                                    __float_as_uint(wt));
        }
    }
}

__global__ void k_ncount(const uint2* __restrict__ stage, const int* __restrict__ gcur,
                         int* __restrict__ counts) {
    __shared__ int lh[BUCK_NODES];
    int b = blockIdx.x;
    int tid = threadIdx.x;
    #pragma unroll
    for (int r = 0; r < BUCK_NODES / 256; ++r) lh[r * 256 + tid] = 0;
    __syncthreads();
    int cnt = gcur[b];
    const uint2* sb = stage + (ll)b * BUCK_CAP;
    for (int i = tid; i < cnt; i += 256)
        atomicAdd(&lh[(sb[i].x >> 19) & (BUCK_NODES - 1)], 1);
    __syncthreads();
    int nbase = b * BUCK_NODES;
    #pragma unroll
    for (int r = 0; r < BUCK_NODES / 256; ++r) {
        int i = r * 256 + tid;
        int n = nbase + i;
        if (n < N_NODES) counts[n] = lh[i];
    }
}

#define SCAN_ELEMS 1024
__global__ void k_scan1(int* __restrict__ data, int* __restrict__ blocksums) {
    __shared__ int tmp[256];
    int b = blockIdx.x;
    int t = threadIdx.x;
    int base = b * SCAN_ELEMS + t * 4;
    int v[4];
    #pragma unroll
    for (int k = 0; k < 4; ++k) {
        int i = base + k;
        v[k] = (i < N_NODES) ? data[i] : 0;
    }
    int tsum = v[0] + v[1] + v[2] + v[3];
    tmp[t] = tsum;
    __syncthreads();
    for (int off = 1; off < 256; off <<= 1) {
        int x = (t >= off) ? tmp[t - off] : 0;
        __syncthreads();
        tmp[t] += x;
        __syncthreads();
    }
    int run = tmp[t] - tsum;
    #pragma unroll
    for (int k = 0; k < 4; ++k) {
        int i = base + k;
        if (i < N_NODES) data[i] = run;
        run += v[k];
    }
    if (t == 255) blocksums[b] = tmp[255];
}

__global__ void k_scan2(int* __restrict__ blocksums, int nb) {
    __shared__ int tmp[512];
    int t = threadIdx.x;
    int v = (t < nb) ? blocksums[t] : 0;
    tmp[t] = v;
    __syncthreads();
    for (int off = 1; off < 512; off <<= 1) {
        int x = (t >= off) ? tmp[t - off] : 0;
        __syncthreads();
        tmp[t] += x;
        __syncthreads();
    }
    if (t < nb) blocksums[t] = tmp[t] - v;
}

__global__ void k_scan3(int* __restrict__ rowptr, const int* __restrict__ blocksums) {
    int stride = gridDim.x * blockDim.x;
    for (int i = blockIdx.x * blockDim.x + threadIdx.x; i < N_NODES; i += stride)
        rowptr[i] = rowptr[i] + blocksums[i >> 10];
    if (blockIdx.x == 0 && threadIdx.x == 0) rowptr[N_NODES] = N_EDGES;
}

__global__ void k_place(const uint2* __restrict__ stage, const int* __restrict__ gcur,
                        const int* __restrict__ rowptr, int2* __restrict__ csr) {
    __shared__ int lpos[BUCK_NODES];
    int b = blockIdx.x;
    int tid = threadIdx.x;
    int nbase = b * BUCK_NODES;
    #pragma unroll
    for (int r = 0; r < BUCK_NODES / 256; ++r) {
        int i = r * 256 + tid;
        int n = nbase + i;
        lpos[i] = (n < N_NODES) ? rowptr[n] : 0;
    }
    __syncthreads();
    int cnt = gcur[b];
    const uint2* sb = stage + (ll)b * BUCK_CAP;
    for (int i = tid; i < cnt; i += 256) {
        uint2 e = sb[i];
        int ldst = (e.x >> 19) & (BUCK_NODES - 1);
        int s = e.x & 0x7FFFF;
        int pos = atomicAdd(&lpos[ldst], 1);
        csr[pos] = make_int2(s, (int)e.y);
    }
}

// ---------------------------------------------------------------------------
// Propagation kernels (unchanged from round 5).
// ---------------------------------------------------------------------------

__device__ __forceinline__ const f4* tab_row(const f4* u4, const f4* i4, int s) {
    return (s < N_USERS) ? (u4 + (ll)s * 16) : (i4 + (ll)(s - N_USERS) * 16);
}

// Layer 1: 4 nodes/wave, 16 lanes x f4 each; gathers fp32 tables; writes bf16 x1.
__global__ void k_prop1(const f4* __restrict__ u4, const f4* __restrict__ i4,
                        const int* __restrict__ rowptr,
                        const int2* __restrict__ csr,
                        us4* __restrict__ x1b) {
    int wave = (blockIdx.x * blockDim.x + threadIdx.x) >> 6;
    int lane = threadIdx.x & 63;
    int sub = lane >> 4;
    int fl  = lane & 15;
    int nwaves = (gridDim.x * blockDim.x) >> 6;
    for (int nb = wave * 4; nb < N_NODES; nb += nwaves * 4) {
        int n = nb + sub;
        int start = rowptr[n];
        int end   = rowptr[n + 1];
        int deg = end - start;
        f4 s = {0.f, 0.f, 0.f, 0.f};
        if (deg > 0) {
            int lastj = end - 1;
            int j1 = start + 1 < end ? start + 1 : lastj;
            int j2 = start + 2 < end ? start + 2 : lastj;
            int j3 = start + 3 < end ? start + 3 : lastj;
            int2 e0 = csr[start];
            int2 e1 = csr[j1];
            int2 e2 = csr[j2];
            int2 e3 = csr[j3];
            float w0 = __int_as_float(e0.y);
            float w1 = (deg > 1) ? __int_as_float(e1.y) : 0.f;
            float w2 = (deg > 2) ? __int_as_float(e2.y) : 0.f;
            float w3 = (deg > 3) ? __int_as_float(e3.y) : 0.f;
            f4 v0 = tab_row(u4, i4, e0.x)[fl];
            f4 v1 = tab_row(u4, i4, e1.x)[fl];
            f4 v2 = tab_row(u4, i4, e2.x)[fl];
            f4 v3 = tab_row(u4, i4, e3.x)[fl];
            s = w0 * v0 + w1 * v1 + w2 * v2 + w3 * v3;
            int j = start + 4;
            for (; j + 1 < end; j += 2) {
                int2 a = csr[j];
                int2 b = csr[j + 1];
                f4 va = tab_row(u4, i4, a.x)[fl];
                f4 vb = tab_row(u4, i4, b.x)[fl];
                s += __int_as_float(a.y) * va;
                s += __int_as_float(b.y) * vb;
            }
            if (j < end) {
                int2 a = csr[j];
                s += __int_as_float(a.y) * tab_row(u4, i4, a.x)[fl];
            }
        }
        us4 o;
        #pragma unroll
        for (int k = 0; k < 4; ++k) o[k] = f2bf(s[k]);
        x1b[(ll)n * 16 + fl] = o;
    }
}

// Layer 2: 8 nodes/wave, 8 lanes x bf16x8 each; gathers bf16 x1; writes bf16 x2.
__global__ void k_prop2(const us8* __restrict__ x1b,
                        const int* __restrict__ rowptr,
                        const int2* __restrict__ csr,
                        us8* __restrict__ x2b) {
    int wave = (blockIdx.x * blockDim.x + threadIdx.x) >> 6;
    int lane = threadIdx.x & 63;
    int sub = lane >> 3;
    int fl  = lane & 7;
    int nwaves = (gridDim.x * blockDim.x) >> 6;
    for (int nb = wave * 8; nb < N_NODES; nb += nwaves * 8) {
        int n = nb + sub;
        int start = rowptr[n];
        int end   = rowptr[n + 1];
        int deg = end - start;
        f8 s = {0.f, 0.f, 0.f, 0.f, 0.f, 0.f, 0.f, 0.f};
        if (deg > 0) {
            int lastj = end - 1;
            int j1 = start + 1 < end ? start + 1 : lastj;
            int j2 = start + 2 < end ? start + 2 : lastj;
            int j3 = start + 3 < end ? start + 3 : lastj;
            int2 e0 = csr[start];
            int2 e1 = csr[j1];
            int2 e2 = csr[j2];
            int2 e3 = csr[j3];
            float w0 = __int_as_float(e0.y);
            float w1 = (deg > 1) ? __int_as_float(e1.y) : 0.f;
            float w2 = (deg > 2) ? __int_as_float(e2.y) : 0.f;
            float w3 = (deg > 3) ? __int_as_float(e3.y) : 0.f;
            us8 v0 = x1b[(ll)e0.x * 8 + fl];
            us8 v1 = x1b[(ll)e1.x * 8 + fl];
            us8 v2 = x1b[(ll)e2.x * 8 + fl];
            us8 v3 = x1b[(ll)e3.x * 8 + fl];
            fma8(s, w0, v0);
            fma8(s, w1, v1);
            fma8(s, w2, v2);
            fma8(s, w3, v3);
            int j = start + 4;
            for (; j + 1 < end; j += 2) {
                int2 a = csr[j];
                int2 b = csr[j + 1];
                us8 va = x1b[(ll)a.x * 8 + fl];
                us8 vb = x1b[(ll)b.x * 8 + fl];
                fma8(s, __int_as_float(a.y), va);
                fma8(s, __int_as_float(b.y), vb);
            }
            if (j < end) {
                int2 a = csr[j];
                us8 va = x1b[(ll)a.x * 8 + fl];
                fma8(s, __int_as_float(a.y), va);
            }
        }
        us8 o;
        #pragma unroll
        for (int k = 0; k < 8; ++k) o[k] = f2bf(s[k]);
        x2b[(ll)n * 8 + fl] = o;
    }
}

// Final: gathers x3 from bf16 x2; acc = 0.25*(x0 + x1 + x2 + x3) in fp32.
__global__ void k_final(const f4* __restrict__ u4, const f4* __restrict__ i4,
                        const us8* __restrict__ x1b, const us8* __restrict__ x2b,
                        const int* __restrict__ rowptr,
                        const int2* __restrict__ csr,
                        f4* __restrict__ acc) {
    int wave = (blockIdx.x * blockDim.x + threadIdx.x) >> 6;
    int lane = threadIdx.x & 63;
    int sub = lane >> 3;
    int fl  = lane & 7;
    int nwaves = (gridDim.x * blockDim.x) >> 6;
    for (int nb = wave * 8; nb < N_NODES; nb += nwaves * 8) {
        int n = nb + sub;
        int start = rowptr[n];
        int end   = rowptr[n + 1];
        int deg = end - start;
        f8 s = {0.f, 0.f, 0.f, 0.f, 0.f, 0.f, 0.f, 0.f};
        if (deg > 0) {
            int lastj = end - 1;
            int j1 = start + 1 < end ? start + 1 : lastj;
            int j2 = start + 2 < end ? start + 2 : lastj;
            int j3 = start + 3 < end ? start + 3 : lastj;
            int2 e0 = csr[start];
            int2 e1 = csr[j1];
            int2 e2 = csr[j2];
            int2 e3 = csr[j3];
            float w0 = __int_as_float(e0.y);
            float w1 = (deg > 1) ? __int_as_float(e1.y) : 0.f;
            float w2 = (deg > 2) ? __int_as_float(e2.y) : 0.f;
            float w3 = (deg > 3) ? __int_as_float(e3.y) : 0.f;
            us8 v0 = x2b[(ll)e0.x * 8 + fl];
            us8 v1 = x2b[(ll)e1.x * 8 + fl];
            us8 v2 = x2b[(ll)e2.x * 8 + fl];
            us8 v3 = x2b[(ll)e3.x * 8 + fl];
            fma8(s, w0, v0);
            fma8(s, w1, v1);
            fma8(s, w2, v2);
            fma8(s, w3, v3);
            int j = start + 4;
            for (; j + 1 < end; j += 2) {
                int2 a = csr[j];
                int2 b = csr[j + 1];
                us8 va = x2b[(ll)a.x * 8 + fl];
                us8 vb = x2b[(ll)b.x * 8 + fl];
                fma8(s, __int_as_float(a.y), va);
                fma8(s, __int_as_float(b.y), vb);
            }
            if (j < end) {
                int2 a = csr[j];
                us8 va = x2b[(ll)a.x * 8 + fl];
                fma8(s, __int_as_float(a.y), va);
            }
        }
        const f4* trow = tab_row(u4, i4, n);
        f4 x0lo = __builtin_nontemporal_load(&trow[fl * 2]);
        f4 x0hi = __builtin_nontemporal_load(&trow[fl * 2 + 1]);
        ll idx8 = (ll)n * 8 + fl;
        us8 x1v = __builtin_nontemporal_load(&x1b[idx8]);
        us8 x2v = x2b[idx8];
        f4 rlo, rhi;
        #pragma unroll
        for (int k = 0; k < 4; ++k)
            rlo[k] = 0.25f * (x0lo[k] + bf2f(x1v[k]) + bf2f(x2v[k]) + s[k]);
        #pragma unroll
        for (int k = 0; k < 4; ++k)
            rhi[k] = 0.25f * (x0hi[k] + bf2f(x1v[k + 4]) + bf2f(x2v[k + 4]) + s[k + 4]);
        f4* arow = acc + (ll)n * 16;
        __builtin_nontemporal_store(rlo, &arow[fl * 2]);
        __builtin_nontemporal_store(rhi, &arow[fl * 2 + 1]);
    }
}

// ---------------------------------------------------------------------------
// Fallback (round-1 atomic path) in case ws is too small.
// ---------------------------------------------------------------------------

__global__ void fb_init(const float* __restrict__ user_w,
                        const float* __restrict__ item_w,
                        float* __restrict__ acc, float* __restrict__ xcur) {
    const ll total4 = (ll)N_NODES * EMB_DIM / 4;
    const ll user4 = (ll)N_USERS * EMB_DIM / 4;
    const float4* uw = (const float4*)user_w;
    const float4* iw = (const float4*)item_w;
    float4* a4 = (float4*)acc;
    float4* x4 = (float4*)xcur;
    ll stride = (ll)gridDim.x * blockDim.x;
    for (ll i = (ll)blockIdx.x * blockDim.x + threadIdx.x; i < total4; i += stride) {
        float4 v = (i < user4) ? uw[i] : iw[i - user4];
        x4[i] = v;
        a4[i] = make_float4(0.25f * v.x, 0.25f * v.y, 0.25f * v.z, 0.25f * v.w);
    }
}
__global__ void fb_zero(float* __restrict__ p) {
    const ll total4 = (ll)N_NODES * EMB_DIM / 4;
    float4* p4 = (float4*)p;
    ll stride = (ll)gridDim.x * blockDim.x;
    float4 z = make_float4(0.f, 0.f, 0.f, 0.f);
    for (ll i = (ll)blockIdx.x * blockDim.x + threadIdx.x; i < total4; i += stride)
        p4[i] = z;
}
__global__ void fb_scatter(const float* __restrict__ xcur, const int* __restrict__ src,
                           const int* __restrict__ dst, const float* __restrict__ w,
                           float* __restrict__ xnext) {
    const int gpb = blockDim.x >> 6;
    const int d = threadIdx.x & 63;
    int eg = blockIdx.x * gpb + (threadIdx.x >> 6);
    const int estride = gridDim.x * gpb;
    for (int e = eg; e < N_EDGES; e += estride) {
        int s = src[e]; int t = dst[e]; float wt = w[e];
        atomicAdd(&xnext[(ll)t * EMB_DIM + d], xcur[(ll)s * EMB_DIM + d] * wt);
    }
}
__global__ void fb_accadd(const float* __restrict__ xn, float* __restrict__ acc) {
    const ll total4 = (ll)N_NODES * EMB_DIM / 4;
    const float4* x4 = (const float4*)xn;
    float4* a4 = (float4*)acc;
    ll stride = (ll)gridDim.x * blockDim.x;
    for (ll i = (ll)blockIdx.x * blockDim.x + threadIdx.x; i < total4; i += stride) {
        float4 v = x4[i]; float4 a = a4[i];
        a.x += 0.25f * v.x; a.y += 0.25f * v.y;
        a.z += 0.25f * v.z; a.w += 0.25f * v.w;
        a4[i] = a;
    }
}

// ---------------------------------------------------------------------------

extern "C" void kernel_launch(void* const* d_in, const int* in_sizes, int n_in,
                              void* d_out, int out_size, void* d_ws, size_t ws_size,
                              hipStream_t stream) {
    const float* user_w = (const float*)d_in[0];
    const float* item_w = (const float*)d_in[1];
    const int*   eidx   = (const int*)d_in[2];     // [2, N_EDGES] int32
    const float* ew     = (const float*)d_in[3];   // [N_EDGES]
    const int* src = eidx;
    const int* dst = eidx + N_EDGES;

    const size_t xb_bf = (size_t)N_NODES * EMB_DIM * 2;          // 64 MB each
    size_t off = 2 * xb_bf;
    size_t stage_off  = off;   off += (size_t)NBUCK * BUCK_CAP * 8;   // ~12 MB
    size_t csr_off    = off;   off += (size_t)N_EDGES * 8;            // 9.6 MB
    size_t rowptr_off = off;   off += (size_t)(N_NODES + 1) * 4;      // 2 MB
    size_t gcur_off   = off;   off += 256 * 4;
    size_t bsums_off  = off;   off += 4096;
    const size_t need = off;

    const int blk = 256;

    if (ws_size >= need) {
        us4*   x1b4  = (us4*)d_ws;
        us8*   x1b   = (us8*)d_ws;
        us8*   x2b   = (us8*)((char*)d_ws + xb_bf);
        uint2* stage = (uint2*)((char*)d_ws + stage_off);
        int2*  csr   = (int2*)((char*)d_ws + csr_off);
        int*   rowptr = (int*)((char*)d_ws + rowptr_off);
        int*   gcur   = (int*)((char*)d_ws + gcur_off);
        int*   bsums  = (int*)((char*)d_ws + bsums_off);
        f4*    acc    = (f4*)d_out;
        const f4* u4 = (const f4*)user_w;
        const f4* i4 = (const f4*)item_w;

        const int nb_scan = (N_NODES + SCAN_ELEMS - 1) / SCAN_ELEMS;  // 489
        const int nb_sort = (N_EDGES + CHUNK - 1) / CHUNK;            // 293

        // --- CSR build (locality-staged) ---
        k_init<<<1, 256, 0, stream>>>(gcur);
        k_bsort<<<nb_sort, blk, 0, stream>>>(src, dst, ew, gcur, stage);
        k_ncount<<<NBUCK, blk, 0, stream>>>(stage, gcur, rowptr);
        k_scan1<<<nb_scan, 256, 0, stream>>>(rowptr, bsums);
        k_scan2<<<1, 512, 0, stream>>>(bsums, nb_scan);
        k_scan3<<<2048, blk, 0, stream>>>(rowptr, bsums);
        k_place<<<NBUCK, blk, 0, stream>>>(stage, gcur, rowptr, csr);

        // --- layers ---
        const int grid_l = 4096;
        k_prop1<<<grid_l, blk, 0, stream>>>(u4, i4, rowptr, csr, x1b4);
        k_prop2<<<grid_l, blk, 0, stream>>>(x1b, rowptr, csr, x2b);
        k_final<<<grid_l, blk, 0, stream>>>(u4, i4, x1b, x2b, rowptr, csr, acc);
    } else {
        float* acc = (float*)d_out;
        float* xcur = (float*)d_ws;
        float* xnext = xcur + (ll)N_NODES * EMB_DIM;
        fb_init<<<2048, blk, 0, stream>>>(user_w, item_w, acc, xcur);
        for (int layer = 0; layer < 3; ++layer) {
            fb_zero<<<2048, blk, 0, stream>>>(xnext);
            fb_scatter<<<4096, blk, 0, stream>>>(xcur, src, dst, ew, xnext);
            fb_accadd<<<2048, blk, 0, stream>>>(xnext, acc);
            float* tmp = xcur; xcur = xnext; xnext = tmp;
        }
    }
}

// Round 7
// 244.149 us; speedup vs baseline: 4.3928x; 1.0575x over previous
//
#include <hip/hip_runtime.h>

#define N_USERS 100000
#define N_ITEMS 400000
#define N_NODES 500000
#define EMB_DIM 64
#define N_EDGES 1200000

#define BUCK_SHIFT 11
#define BUCK_NODES 2048                      // nodes per bucket
#define NBUCK 245                            // ceil(500000/2048)
#define BUCK_CAP 6144                        // >= max bucket count (mean 4898, +17 sigma)
#define CHUNK 4096                           // edges per k_bsort block

typedef long long ll;
typedef float f4 __attribute__((ext_vector_type(4)));
typedef float f8 __attribute__((ext_vector_type(8)));
typedef unsigned short u16;
typedef u16 us8 __attribute__((ext_vector_type(8)));   // 16 B (8 bf16)

__device__ __forceinline__ u16 f2bf(float f) {
    unsigned u = __float_as_uint(f);
    u += 0x7FFF + ((u >> 16) & 1);          // round-to-nearest-even
    return (u16)(u >> 16);
}
__device__ __forceinline__ float bf2f(u16 h) {
    return __uint_as_float(((unsigned)h) << 16);
}
__device__ __forceinline__ void fma8(f8& s, float w, us8 v) {
    #pragma unroll
    for (int k = 0; k < 8; ++k) s[k] += w * bf2f(v[k]);
}

// ---------------------------------------------------------------------------
// CSR build, locality-staged (unchanged from round 6).
// ---------------------------------------------------------------------------

__global__ void k_init(int* __restrict__ gcur) {
    if (threadIdx.x < 256) gcur[threadIdx.x] = 0;
}

__global__ void k_bsort(const int* __restrict__ src, const int* __restrict__ dst,
                        const float* __restrict__ w,
                        int* __restrict__ gcur, uint2* __restrict__ stage) {
    __shared__ int lhist[256];
    __shared__ int gbase_s[256];
    __shared__ int lcur[256];
    int tid = threadIdx.x;
    lhist[tid] = 0;
    __syncthreads();
    int c0 = blockIdx.x * CHUNK;
    int c1 = c0 + CHUNK < N_EDGES ? c0 + CHUNK : N_EDGES;
    #pragma unroll
    for (int r = 0; r < CHUNK / 256; ++r) {
        int e = c0 + r * 256 + tid;
        if (e < c1) atomicAdd(&lhist[dst[e] >> BUCK_SHIFT], 1);
    }
    __syncthreads();
    if (tid < NBUCK) {
        gbase_s[tid] = atomicAdd(&gcur[tid], lhist[tid]);
        lcur[tid] = 0;
    }
    __syncthreads();
    #pragma unroll
    for (int r = 0; r < CHUNK / 256; ++r) {
        int e = c0 + r * 256 + tid;
        if (e < c1) {
            int s = src[e];
            int d = dst[e];
            float wt = w[e];
            int b = d >> BUCK_SHIFT;
            int k = atomicAdd(&lcur[b], 1);
            ll idx = (ll)b * BUCK_CAP + gbase_s[b] + k;
            stage[idx] = make_uint2((unsigned)s | ((unsigned)(d & (BUCK_NODES - 1)) << 19),
                                    __float_as_uint(wt));
        }
    }
}

__global__ void k_ncount(const uint2* __restrict__ stage, const int* __restrict__ gcur,
                         int* __restrict__ counts) {
    __shared__ int lh[BUCK_NODES];
    int b = blockIdx.x;
    int tid = threadIdx.x;
    #pragma unroll
    for (int r = 0; r < BUCK_NODES / 256; ++r) lh[r * 256 + tid] = 0;
    __syncthreads();
    int cnt = gcur[b];
    const uint2* sb = stage + (ll)b * BUCK_CAP;
    for (int i = tid; i < cnt; i += 256)
        atomicAdd(&lh[(sb[i].x >> 19) & (BUCK_NODES - 1)], 1);
    __syncthreads();
    int nbase = b * BUCK_NODES;
    #pragma unroll
    for (int r = 0; r < BUCK_NODES / 256; ++r) {
        int i = r * 256 + tid;
        int n = nbase + i;
        if (n < N_NODES) counts[n] = lh[i];
    }
}

#define SCAN_ELEMS 1024
__global__ void k_scan1(int* __restrict__ data, int* __restrict__ blocksums) {
    __shared__ int tmp[256];
    int b = blockIdx.x;
    int t = threadIdx.x;
    int base = b * SCAN_ELEMS + t * 4;
    int v[4];
    #pragma unroll
    for (int k = 0; k < 4; ++k) {
        int i = base + k;
        v[k] = (i < N_NODES) ? data[i] : 0;
    }
    int tsum = v[0] + v[1] + v[2] + v[3];
    tmp[t] = tsum;
    __syncthreads();
    for (int off = 1; off < 256; off <<= 1) {
        int x = (t >= off) ? tmp[t - off] : 0;
        __syncthreads();
        tmp[t] += x;
        __syncthreads();
    }
    int run = tmp[t] - tsum;
    #pragma unroll
    for (int k = 0; k < 4; ++k) {
        int i = base + k;
        if (i < N_NODES) data[i] = run;
        run += v[k];
    }
    if (t == 255) blocksums[b] = tmp[255];
}

__global__ void k_scan2(int* __restrict__ blocksums, int nb) {
    __shared__ int tmp[512];
    int t = threadIdx.x;
    int v = (t < nb) ? blocksums[t] : 0;
    tmp[t] = v;
    __syncthreads();
    for (int off = 1; off < 512; off <<= 1) {
        int x = (t >= off) ? tmp[t - off] : 0;
        __syncthreads();
        tmp[t] += x;
        __syncthreads();
    }
    if (t < nb) blocksums[t] = tmp[t] - v;
}

__global__ void k_scan3(int* __restrict__ rowptr, const int* __restrict__ blocksums) {
    int stride = gridDim.x * blockDim.x;
    for (int i = blockIdx.x * blockDim.x + threadIdx.x; i < N_NODES; i += stride)
        rowptr[i] = rowptr[i] + blocksums[i >> 10];
    if (blockIdx.x == 0 && threadIdx.x == 0) rowptr[N_NODES] = N_EDGES;
}

__global__ void k_place(const uint2* __restrict__ stage, const int* __restrict__ gcur,
                        const int* __restrict__ rowptr, int2* __restrict__ csr) {
    __shared__ int lpos[BUCK_NODES];
    int b = blockIdx.x;
    int tid = threadIdx.x;
    int nbase = b * BUCK_NODES;
    #pragma unroll
    for (int r = 0; r < BUCK_NODES / 256; ++r) {
        int i = r * 256 + tid;
        int n = nbase + i;
        lpos[i] = (n < N_NODES) ? rowptr[n] : 0;
    }
    __syncthreads();
    int cnt = gcur[b];
    const uint2* sb = stage + (ll)b * BUCK_CAP;
    for (int i = tid; i < cnt; i += 256) {
        uint2 e = sb[i];
        int ldst = (e.x >> 19) & (BUCK_NODES - 1);
        int s = e.x & 0x7FFFF;
        int pos = atomicAdd(&lpos[ldst], 1);
        csr[pos] = make_int2(s, (int)e.y);
    }
}

// ---------------------------------------------------------------------------
// x0 fp32 -> bf16 conversion (streaming; nt loads keep dead tables out of L3)
// ---------------------------------------------------------------------------

__global__ void k_conv(const f4* __restrict__ u4, const f4* __restrict__ i4,
                       us8* __restrict__ x0b) {
    const int total = N_NODES * 8;           // us8 slots
    const int user8 = N_USERS * 8;
    int stride = gridDim.x * blockDim.x;
    for (int i = blockIdx.x * blockDim.x + threadIdx.x; i < total; i += stride) {
        const f4* p = (i < user8) ? (u4 + (ll)i * 2) : (i4 + (ll)(i - user8) * 2);
        f4 lo = __builtin_nontemporal_load(p);
        f4 hi = __builtin_nontemporal_load(p + 1);
        us8 o;
        #pragma unroll
        for (int k = 0; k < 4; ++k) { o[k] = f2bf(lo[k]); o[k + 4] = f2bf(hi[k]); }
        x0b[i] = o;
    }
}

// ---------------------------------------------------------------------------
// Propagation: 8 nodes/wave, 8 lanes x bf16x8 per node; batch-of-4 gathers.
// ---------------------------------------------------------------------------

__device__ __forceinline__ f8 gather8(const us8* __restrict__ xin,
                                      const int* __restrict__ rowptr,
                                      const int2* __restrict__ csr,
                                      int n, int fl) {
    int start = rowptr[n];
    int end   = rowptr[n + 1];
    int deg = end - start;
    f8 s = {0.f, 0.f, 0.f, 0.f, 0.f, 0.f, 0.f, 0.f};
    if (deg > 0) {
        int lastj = end - 1;
        int j1 = start + 1 < end ? start + 1 : lastj;
        int j2 = start + 2 < end ? start + 2 : lastj;
        int j3 = start + 3 < end ? start + 3 : lastj;
        int2 e0 = csr[start];
        int2 e1 = csr[j1];
        int2 e2 = csr[j2];
        int2 e3 = csr[j3];
        float w0 = __int_as_float(e0.y);
        float w1 = (deg > 1) ? __int_as_float(e1.y) : 0.f;
        float w2 = (deg > 2) ? __int_as_float(e2.y) : 0.f;
        float w3 = (deg > 3) ? __int_as_float(e3.y) : 0.f;
        us8 v0 = xin[(ll)e0.x * 8 + fl];
        us8 v1 = xin[(ll)e1.x * 8 + fl];
        us8 v2 = xin[(ll)e2.x * 8 + fl];
        us8 v3 = xin[(ll)e3.x * 8 + fl];
        fma8(s, w0, v0);
        fma8(s, w1, v1);
        fma8(s, w2, v2);
        fma8(s, w3, v3);
        int j = start + 4;
        for (; j + 1 < end; j += 2) {
            int2 a = csr[j];
            int2 b = csr[j + 1];
            us8 va = xin[(ll)a.x * 8 + fl];
            us8 vb = xin[(ll)b.x * 8 + fl];
            fma8(s, __int_as_float(a.y), va);
            fma8(s, __int_as_float(b.y), vb);
        }
        if (j < end) {
            int2 a = csr[j];
            us8 va = xin[(ll)a.x * 8 + fl];
            fma8(s, __int_as_float(a.y), va);
        }
    }
    return s;
}

// Generic layer: xout = A xin (both bf16).
__global__ void k_prop(const us8* __restrict__ xin,
                       const int* __restrict__ rowptr,
                       const int2* __restrict__ csr,
                       us8* __restrict__ xout) {
    int wave = (blockIdx.x * blockDim.x + threadIdx.x) >> 6;
    int lane = threadIdx.x & 63;
    int sub = lane >> 3;
    int fl  = lane & 7;
    int nwaves = (gridDim.x * blockDim.x) >> 6;
    for (int nb = wave * 8; nb < N_NODES; nb += nwaves * 8) {
        int n = nb + sub;                      // N_NODES % 8 == 0
        f8 s = gather8(xin, rowptr, csr, n, fl);
        us8 o;
        #pragma unroll
        for (int k = 0; k < 8; ++k) o[k] = f2bf(s[k]);
        xout[(ll)n * 8 + fl] = o;
    }
}

// Final: gathers x3 from bf16 x2; acc = 0.25*(x0 + x1 + x2 + x3) in fp32.
__global__ void k_final(const us8* __restrict__ x0b,
                        const us8* __restrict__ x1b, const us8* __restrict__ x2b,
                        const int* __restrict__ rowptr,
                        const int2* __restrict__ csr,
                        f4* __restrict__ acc) {
    int wave = (blockIdx.x * blockDim.x + threadIdx.x) >> 6;
    int lane = threadIdx.x & 63;
    int sub = lane >> 3;
    int fl  = lane & 7;
    int nwaves = (gridDim.x * blockDim.x) >> 6;
    for (int nb = wave * 8; nb < N_NODES; nb += nwaves * 8) {
        int n = nb + sub;
        f8 s = gather8(x2b, rowptr, csr, n, fl);
        ll idx8 = (ll)n * 8 + fl;
        us8 x0v = x0b[idx8];
        us8 x1v = __builtin_nontemporal_load(&x1b[idx8]);
        us8 x2v = x2b[idx8];
        f4 rlo, rhi;
        #pragma unroll
        for (int k = 0; k < 4; ++k)
            rlo[k] = 0.25f * (bf2f(x0v[k]) + bf2f(x1v[k]) + bf2f(x2v[k]) + s[k]);
        #pragma unroll
        for (int k = 0; k < 4; ++k)
            rhi[k] = 0.25f * (bf2f(x0v[k + 4]) + bf2f(x1v[k + 4]) + bf2f(x2v[k + 4]) + s[k + 4]);
        f4* arow = acc + (ll)n * 16;
        __builtin_nontemporal_store(rlo, &arow[fl * 2]);
        __builtin_nontemporal_store(rhi, &arow[fl * 2 + 1]);
    }
}

// ---------------------------------------------------------------------------
// Fallback (round-1 atomic path) in case ws is too small.
// ---------------------------------------------------------------------------

__global__ void fb_init(const float* __restrict__ user_w,
                        const float* __restrict__ item_w,
                        float* __restrict__ acc, float* __restrict__ xcur) {
    const ll total4 = (ll)N_NODES * EMB_DIM / 4;
    const ll user4 = (ll)N_USERS * EMB_DIM / 4;
    const float4* uw = (const float4*)user_w;
    const float4* iw = (const float4*)item_w;
    float4* a4 = (float4*)acc;
    float4* x4 = (float4*)xcur;
    ll stride = (ll)gridDim.x * blockDim.x;
    for (ll i = (ll)blockIdx.x * blockDim.x + threadIdx.x; i < total4; i += stride) {
        float4 v = (i < user4) ? uw[i] : iw[i - user4];
        x4[i] = v;
        a4[i] = make_float4(0.25f * v.x, 0.25f * v.y, 0.25f * v.z, 0.25f * v.w);
    }
}
__global__ void fb_zero(float* __restrict__ p) {
    const ll total4 = (ll)N_NODES * EMB_DIM / 4;
    float4* p4 = (float4*)p;
    ll stride = (ll)gridDim.x * blockDim.x;
    float4 z = make_float4(0.f, 0.f, 0.f, 0.f);
    for (ll i = (ll)blockIdx.x * blockDim.x + threadIdx.x; i < total4; i += stride)
        p4[i] = z;
}
__global__ void fb_scatter(const float* __restrict__ xcur, const int* __restrict__ src,
                           const int* __restrict__ dst, const float* __restrict__ w,
                           float* __restrict__ xnext) {
    const int gpb = blockDim.x >> 6;
    const int d = threadIdx.x & 63;
    int eg = blockIdx.x * gpb + (threadIdx.x >> 6);
    const int estride = gridDim.x * gpb;
    for (int e = eg; e < N_EDGES; e += estride) {
        int s = src[e]; int t = dst[e]; float wt = w[e];
        atomicAdd(&xnext[(ll)t * EMB_DIM + d], xcur[(ll)s * EMB_DIM + d] * wt);
    }
}
__global__ void fb_accadd(const float* __restrict__ xn, float* __restrict__ acc) {
    const ll total4 = (ll)N_NODES * EMB_DIM / 4;
    const float4* x4 = (const float4*)xn;
    float4* a4 = (float4*)acc;
    ll stride = (ll)gridDim.x * blockDim.x;
    for (ll i = (ll)blockIdx.x * blockDim.x + threadIdx.x; i < total4; i += stride) {
        float4 v = x4[i]; float4 a = a4[i];
        a.x += 0.25f * v.x; a.y += 0.25f * v.y;
        a.z += 0.25f * v.z; a.w += 0.25f * v.w;
        a4[i] = a;
    }
}

// ---------------------------------------------------------------------------

extern "C" void kernel_launch(void* const* d_in, const int* in_sizes, int n_in,
                              void* d_out, int out_size, void* d_ws, size_t ws_size,
                              hipStream_t stream) {
    const float* user_w = (const float*)d_in[0];
    const float* item_w = (const float*)d_in[1];
    const int*   eidx   = (const int*)d_in[2];     // [2, N_EDGES] int32
    const float* ew     = (const float*)d_in[3];   // [N_EDGES]
    const int* src = eidx;
    const int* dst = eidx + N_EDGES;

    const size_t xb_bf = (size_t)N_NODES * EMB_DIM * 2;          // 64 MB each
    size_t off = 0;
    size_t x0_off     = off;   off += xb_bf;
    size_t x1_off     = off;   off += xb_bf;
    size_t x2_off     = off;   off += xb_bf;
    size_t stage_off  = off;   off += (size_t)NBUCK * BUCK_CAP * 8;   // ~12 MB
    size_t csr_off    = off;   off += (size_t)N_EDGES * 8;            // 9.6 MB
    size_t rowptr_off = off;   off += (size_t)(N_NODES + 1) * 4;      // 2 MB
    size_t gcur_off   = off;   off += 256 * 4;
    size_t bsums_off  = off;   off += 4096;
    const size_t need = off;

    const int blk = 256;

    if (ws_size >= need) {
        us8*   x0b   = (us8*)((char*)d_ws + x0_off);
        us8*   x1b   = (us8*)((char*)d_ws + x1_off);
        us8*   x2b   = (us8*)((char*)d_ws + x2_off);
        uint2* stage = (uint2*)((char*)d_ws + stage_off);
        int2*  csr   = (int2*)((char*)d_ws + csr_off);
        int*   rowptr = (int*)((char*)d_ws + rowptr_off);
        int*   gcur   = (int*)((char*)d_ws + gcur_off);
        int*   bsums  = (int*)((char*)d_ws + bsums_off);
        f4*    acc    = (f4*)d_out;
        const f4* u4 = (const f4*)user_w;
        const f4* i4 = (const f4*)item_w;

        const int nb_scan = (N_NODES + SCAN_ELEMS - 1) / SCAN_ELEMS;  // 489
        const int nb_sort = (N_EDGES + CHUNK - 1) / CHUNK;            // 293

        // --- CSR build (locality-staged) ---
        k_init<<<1, 256, 0, stream>>>(gcur);
        k_bsort<<<nb_sort, blk, 0, stream>>>(src, dst, ew, gcur, stage);
        k_ncount<<<NBUCK, blk, 0, stream>>>(stage, gcur, rowptr);
        k_scan1<<<nb_scan, 256, 0, stream>>>(rowptr, bsums);
        k_scan2<<<1, 512, 0, stream>>>(bsums, nb_scan);
        k_scan3<<<2048, blk, 0, stream>>>(rowptr, bsums);
        k_place<<<NBUCK, blk, 0, stream>>>(stage, gcur, rowptr, csr);

        // --- x0 -> bf16 (right before prop1 so x0b is L3-hot) ---
        k_conv<<<2048, blk, 0, stream>>>(u4, i4, x0b);

        // --- layers ---
        const int grid_l = 4096;
        k_prop<<<grid_l, blk, 0, stream>>>(x0b, rowptr, csr, x1b);
        k_prop<<<grid_l, blk, 0, stream>>>(x1b, rowptr, csr, x2b);
        k_final<<<grid_l, blk, 0, stream>>>(x0b, x1b, x2b, rowptr, csr, acc);
    } else {
        float* acc = (float*)d_out;
        float* xcur = (float*)d_ws;
        float* xnext = xcur + (ll)N_NODES * EMB_DIM;
        fb_init<<<2048, blk, 0, stream>>>(user_w, item_w, acc, xcur);
        for (int layer = 0; layer < 3; ++layer) {
            fb_zero<<<2048, blk, 0, stream>>>(xnext);
            fb_scatter<<<4096, blk, 0, stream>>>(xcur, src, dst, ew, xnext);
            fb_accadd<<<2048, blk, 0, stream>>>(xnext, acc);
            float* tmp = xcur; xcur = xnext; xnext = tmp;
        }
    }
}

// Round 8
// 236.953 us; speedup vs baseline: 4.5263x; 1.0304x over previous
//
#include <hip/hip_runtime.h>

#define N_USERS 100000
#define N_ITEMS 400000
#define N_NODES 500000
#define EMB_DIM 64
#define N_EDGES 1200000

#define BUCK_SHIFT 11
#define BUCK_NODES 2048                      // nodes per bucket
#define NBUCK 245                            // ceil(500000/2048)
#define BUCK_CAP 6144                        // >= max bucket count (mean 4898, +17 sigma)
#define CHUNK 4096                           // edges per bsort block
#define NB_SORT 293                          // ceil(N_EDGES/CHUNK)
#define NB_CONV 1024                         // conv blocks appended to bsort grid

typedef long long ll;
typedef float f4 __attribute__((ext_vector_type(4)));
typedef float f8 __attribute__((ext_vector_type(8)));
typedef unsigned short u16;
typedef u16 us8 __attribute__((ext_vector_type(8)));   // 16 B (8 bf16)

__device__ __forceinline__ u16 f2bf(float f) {
    unsigned u = __float_as_uint(f);
    u += 0x7FFF + ((u >> 16) & 1);          // round-to-nearest-even
    return (u16)(u >> 16);
}
__device__ __forceinline__ float bf2f(u16 h) {
    return __uint_as_float(((unsigned)h) << 16);
}
__device__ __forceinline__ void fma8(f8& s, float w, us8 v) {
    #pragma unroll
    for (int k = 0; k < 8; ++k) s[k] += w * bf2f(v[k]);
}

// ---------------------------------------------------------------------------
// CSR build, locality-staged. k_bsort fused with x0->bf16 conversion.
// ---------------------------------------------------------------------------

__global__ void k_init(int* __restrict__ gcur) {
    if (threadIdx.x < 256) gcur[threadIdx.x] = 0;
}

__global__ void k_bsort_conv(const int* __restrict__ src, const int* __restrict__ dst,
                             const float* __restrict__ w,
                             int* __restrict__ gcur, uint2* __restrict__ stage,
                             const f4* __restrict__ u4, const f4* __restrict__ i4,
                             us8* __restrict__ x0b) {
    __shared__ int lhist[256];
    __shared__ int gbase_s[256];
    __shared__ int lcur[256];
    int tid = threadIdx.x;

    if (blockIdx.x >= NB_SORT) {
        // ---- conv portion: x0 fp32 -> bf16, streaming ----
        const int total = N_NODES * 8;       // us8 slots
        const int user8 = N_USERS * 8;
        int i0 = (blockIdx.x - NB_SORT) * 256 + tid;
        int stride = NB_CONV * 256;
        for (int i = i0; i < total; i += stride) {
            const f4* p = (i < user8) ? (u4 + (ll)i * 2) : (i4 + (ll)(i - user8) * 2);
            f4 lo = __builtin_nontemporal_load(p);
            f4 hi = __builtin_nontemporal_load(p + 1);
            us8 o;
            #pragma unroll
            for (int k = 0; k < 4; ++k) { o[k] = f2bf(lo[k]); o[k + 4] = f2bf(hi[k]); }
            x0b[i] = o;
        }
        return;
    }

    // ---- bsort portion ----
    lhist[tid] = 0;
    __syncthreads();
    int c0 = blockIdx.x * CHUNK;
    int c1 = c0 + CHUNK < N_EDGES ? c0 + CHUNK : N_EDGES;
    #pragma unroll
    for (int r = 0; r < CHUNK / 256; ++r) {
        int e = c0 + r * 256 + tid;
        if (e < c1) atomicAdd(&lhist[dst[e] >> BUCK_SHIFT], 1);
    }
    __syncthreads();
    if (tid < NBUCK) {
        gbase_s[tid] = atomicAdd(&gcur[tid], lhist[tid]);
        lcur[tid] = 0;
    }
    __syncthreads();
    #pragma unroll
    for (int r = 0; r < CHUNK / 256; ++r) {
        int e = c0 + r * 256 + tid;
        if (e < c1) {
            int s = src[e];
            int d = dst[e];
            float wt = w[e];
            int b = d >> BUCK_SHIFT;
            int k = atomicAdd(&lcur[b], 1);
            ll idx = (ll)b * BUCK_CAP + gbase_s[b] + k;
            stage[idx] = make_uint2((unsigned)s | ((unsigned)(d & (BUCK_NODES - 1)) << 19),
                                    __float_as_uint(wt));
        }
    }
}

__global__ void k_ncount(const uint2* __restrict__ stage, const int* __restrict__ gcur,
                         int* __restrict__ counts) {
    __shared__ int lh[BUCK_NODES];
    int b = blockIdx.x;
    int tid = threadIdx.x;
    #pragma unroll
    for (int r = 0; r < BUCK_NODES / 256; ++r) lh[r * 256 + tid] = 0;
    __syncthreads();
    int cnt = gcur[b];
    const uint2* sb = stage + (ll)b * BUCK_CAP;
    for (int i = tid; i < cnt; i += 256)
        atomicAdd(&lh[(sb[i].x >> 19) & (BUCK_NODES - 1)], 1);
    __syncthreads();
    int nbase = b * BUCK_NODES;
    #pragma unroll
    for (int r = 0; r < BUCK_NODES / 256; ++r) {
        int i = r * 256 + tid;
        int n = nbase + i;
        if (n < N_NODES) counts[n] = lh[i];
    }
}

#define SCAN_ELEMS 1024
__global__ void k_scan1(int* __restrict__ data, int* __restrict__ blocksums) {
    __shared__ int tmp[256];
    int b = blockIdx.x;
    int t = threadIdx.x;
    int base = b * SCAN_ELEMS + t * 4;
    int v[4];
    #pragma unroll
    for (int k = 0; k < 4; ++k) {
        int i = base + k;
        v[k] = (i < N_NODES) ? data[i] : 0;
    }
    int tsum = v[0] + v[1] + v[2] + v[3];
    tmp[t] = tsum;
    __syncthreads();
    for (int off = 1; off < 256; off <<= 1) {
        int x = (t >= off) ? tmp[t - off] : 0;
        __syncthreads();
        tmp[t] += x;
        __syncthreads();
    }
    int run = tmp[t] - tsum;
    #pragma unroll
    for (int k = 0; k < 4; ++k) {
        int i = base + k;
        if (i < N_NODES) data[i] = run;
        run += v[k];
    }
    if (t == 255) blocksums[b] = tmp[255];
}

__global__ void k_scan2(int* __restrict__ blocksums, int nb) {
    __shared__ int tmp[512];
    int t = threadIdx.x;
    int v = (t < nb) ? blocksums[t] : 0;
    tmp[t] = v;
    __syncthreads();
    for (int off = 1; off < 512; off <<= 1) {
        int x = (t >= off) ? tmp[t - off] : 0;
        __syncthreads();
        tmp[t] += x;
        __syncthreads();
    }
    if (t < nb) blocksums[t] = tmp[t] - v;
}

__global__ void k_scan3(int* __restrict__ rowptr, const int* __restrict__ blocksums) {
    int stride = gridDim.x * blockDim.x;
    for (int i = blockIdx.x * blockDim.x + threadIdx.x; i < N_NODES; i += stride)
        rowptr[i] = rowptr[i] + blocksums[i >> 10];
    if (blockIdx.x == 0 && threadIdx.x == 0) rowptr[N_NODES] = N_EDGES;
}

__global__ void k_place(const uint2* __restrict__ stage, const int* __restrict__ gcur,
                        const int* __restrict__ rowptr, int2* __restrict__ csr) {
    __shared__ int lpos[BUCK_NODES];
    int b = blockIdx.x;
    int tid = threadIdx.x;
    int nbase = b * BUCK_NODES;
    #pragma unroll
    for (int r = 0; r < BUCK_NODES / 256; ++r) {
        int i = r * 256 + tid;
        int n = nbase + i;
        lpos[i] = (n < N_NODES) ? rowptr[n] : 0;
    }
    __syncthreads();
    int cnt = gcur[b];
    const uint2* sb = stage + (ll)b * BUCK_CAP;
    for (int i = tid; i < cnt; i += 256) {
        uint2 e = sb[i];
        int ldst = (e.x >> 19) & (BUCK_NODES - 1);
        int s = e.x & 0x7FFFF;
        int pos = atomicAdd(&lpos[ldst], 1);
        csr[pos] = make_int2(s, (int)e.y);
    }
}

// ---------------------------------------------------------------------------
// Propagation: 2-deep pipelined — each wave handles 16 nodes per iteration
// (two groups of 8), all CSR loads + 8 gathers issued before any FMA.
// Branchless clamped-index / zero-weight handling for deg < 4.
// ---------------------------------------------------------------------------

// Compute clamped batch-of-4 CSR indices for a node.
__device__ __forceinline__ void bidx4(int start, int end,
                                      int& j0, int& j1, int& j2, int& j3) {
    j0 = start < N_EDGES - 1 ? start : N_EDGES - 1;
    int lastj = (end - 1 > start) ? end - 1 : j0;
    j1 = start + 1 < end ? start + 1 : lastj;
    j2 = start + 2 < end ? start + 2 : lastj;
    j3 = start + 3 < end ? start + 3 : lastj;
}

// Remainder loop for deg > 4.
__device__ __forceinline__ void rem4(const us8* __restrict__ xin,
                                     const int2* __restrict__ csr,
                                     int start, int end, int fl, f8& s) {
    int j = start + 4;
    for (; j + 1 < end; j += 2) {
        int2 a = csr[j];
        int2 b = csr[j + 1];
        us8 va = xin[(ll)a.x * 8 + fl];
        us8 vb = xin[(ll)b.x * 8 + fl];
        fma8(s, __int_as_float(a.y), va);
        fma8(s, __int_as_float(b.y), vb);
    }
    if (j < end) {
        int2 a = csr[j];
        us8 va = xin[(ll)a.x * 8 + fl];
        fma8(s, __int_as_float(a.y), va);
    }
}

// Generic layer: xout = A xin (both bf16).
__global__ void k_prop(const us8* __restrict__ xin,
                       const int* __restrict__ rowptr,
                       const int2* __restrict__ csr,
                       us8* __restrict__ xout) {
    int wave = (blockIdx.x * blockDim.x + threadIdx.x) >> 6;
    int lane = threadIdx.x & 63;
    int sub = lane >> 3;
    int fl  = lane & 7;
    int nwaves = (gridDim.x * blockDim.x) >> 6;
    for (int nb = wave * 16; nb < N_NODES; nb += nwaves * 16) {   // N_NODES%16==0
        int na = nb + sub;
        int nc = nb + 8 + sub;
        int sa = rowptr[na], ea = rowptr[na + 1];
        int sc = rowptr[nc], ec = rowptr[nc + 1];
        int dega = ea - sa, degc = ec - sc;
        int ja0, ja1, ja2, ja3, jc0, jc1, jc2, jc3;
        bidx4(sa, ea, ja0, ja1, ja2, ja3);
        bidx4(sc, ec, jc0, jc1, jc2, jc3);
        int2 a0 = csr[ja0], a1 = csr[ja1], a2 = csr[ja2], a3 = csr[ja3];
        int2 c0 = csr[jc0], c1 = csr[jc1], c2 = csr[jc2], c3 = csr[jc3];
        // 8 independent gathers in flight
        us8 va0 = xin[(ll)a0.x * 8 + fl];
        us8 va1 = xin[(ll)a1.x * 8 + fl];
        us8 va2 = xin[(ll)a2.x * 8 + fl];
        us8 va3 = xin[(ll)a3.x * 8 + fl];
        us8 vc0 = xin[(ll)c0.x * 8 + fl];
        us8 vc1 = xin[(ll)c1.x * 8 + fl];
        us8 vc2 = xin[(ll)c2.x * 8 + fl];
        us8 vc3 = xin[(ll)c3.x * 8 + fl];
        float wa0 = (dega > 0) ? __int_as_float(a0.y) : 0.f;
        float wa1 = (dega > 1) ? __int_as_float(a1.y) : 0.f;
        float wa2 = (dega > 2) ? __int_as_float(a2.y) : 0.f;
        float wa3 = (dega > 3) ? __int_as_float(a3.y) : 0.f;
        float wc0 = (degc > 0) ? __int_as_float(c0.y) : 0.f;
        float wc1 = (degc > 1) ? __int_as_float(c1.y) : 0.f;
        float wc2 = (degc > 2) ? __int_as_float(c2.y) : 0.f;
        float wc3 = (degc > 3) ? __int_as_float(c3.y) : 0.f;
        f8 s1 = {0.f, 0.f, 0.f, 0.f, 0.f, 0.f, 0.f, 0.f};
        f8 s2 = {0.f, 0.f, 0.f, 0.f, 0.f, 0.f, 0.f, 0.f};
        fma8(s1, wa0, va0); fma8(s1, wa1, va1);
        fma8(s1, wa2, va2); fma8(s1, wa3, va3);
        fma8(s2, wc0, vc0); fma8(s2, wc1, vc1);
        fma8(s2, wc2, vc2); fma8(s2, wc3, vc3);
        if (dega > 4) rem4(xin, csr, sa, ea, fl, s1);
        if (degc > 4) rem4(xin, csr, sc, ec, fl, s2);
        us8 o1, o2;
        #pragma unroll
        for (int k = 0; k < 8; ++k) { o1[k] = f2bf(s1[k]); o2[k] = f2bf(s2[k]); }
        xout[(ll)na * 8 + fl] = o1;
        xout[(ll)nc * 8 + fl] = o2;
    }
}

// Final: gathers x3 from bf16 x2; acc = 0.25*(x0 + x1 + x2 + x3) in fp32.
__global__ void k_final(const us8* __restrict__ x0b,
                        const us8* __restrict__ x1b, const us8* __restrict__ x2b,
                        const int* __restrict__ rowptr,
                        const int2* __restrict__ csr,
                        f4* __restrict__ acc) {
    int wave = (blockIdx.x * blockDim.x + threadIdx.x) >> 6;
    int lane = threadIdx.x & 63;
    int sub = lane >> 3;
    int fl  = lane & 7;
    int nwaves = (gridDim.x * blockDim.x) >> 6;
    for (int nb = wave * 16; nb < N_NODES; nb += nwaves * 16) {
        int na = nb + sub;
        int nc = nb + 8 + sub;
        int sa = rowptr[na], ea = rowptr[na + 1];
        int sc = rowptr[nc], ec = rowptr[nc + 1];
        int dega = ea - sa, degc = ec - sc;
        int ja0, ja1, ja2, ja3, jc0, jc1, jc2, jc3;
        bidx4(sa, ea, ja0, ja1, ja2, ja3);
        bidx4(sc, ec, jc0, jc1, jc2, jc3);
        int2 a0 = csr[ja0], a1 = csr[ja1], a2 = csr[ja2], a3 = csr[ja3];
        int2 c0 = csr[jc0], c1 = csr[jc1], c2 = csr[jc2], c3 = csr[jc3];
        ll ia = (ll)na * 8 + fl;
        ll ic = (ll)nc * 8 + fl;
        us8 va0 = x2b[(ll)a0.x * 8 + fl];
        us8 va1 = x2b[(ll)a1.x * 8 + fl];
        us8 va2 = x2b[(ll)a2.x * 8 + fl];
        us8 va3 = x2b[(ll)a3.x * 8 + fl];
        us8 vc0 = x2b[(ll)c0.x * 8 + fl];
        us8 vc1 = x2b[(ll)c1.x * 8 + fl];
        us8 vc2 = x2b[(ll)c2.x * 8 + fl];
        us8 vc3 = x2b[(ll)c3.x * 8 + fl];
        us8 x0a = x0b[ia];
        us8 x1a = __builtin_nontemporal_load(&x1b[ia]);
        us8 x2a = x2b[ia];
        us8 x0c = x0b[ic];
        us8 x1c = __builtin_nontemporal_load(&x1b[ic]);
        us8 x2c = x2b[ic];
        float wa0 = (dega > 0) ? __int_as_float(a0.y) : 0.f;
        float wa1 = (dega > 1) ? __int_as_float(a1.y) : 0.f;
        float wa2 = (dega > 2) ? __int_as_float(a2.y) : 0.f;
        float wa3 = (dega > 3) ? __int_as_float(a3.y) : 0.f;
        float wc0 = (degc > 0) ? __int_as_float(c0.y) : 0.f;
        float wc1 = (degc > 1) ? __int_as_float(c1.y) : 0.f;
        float wc2 = (degc > 2) ? __int_as_float(c2.y) : 0.f;
        float wc3 = (degc > 3) ? __int_as_float(c3.y) : 0.f;
        f8 s1 = {0.f, 0.f, 0.f, 0.f, 0.f, 0.f, 0.f, 0.f};
        f8 s2 = {0.f, 0.f, 0.f, 0.f, 0.f, 0.f, 0.f, 0.f};
        fma8(s1, wa0, va0); fma8(s1, wa1, va1);
        fma8(s1, wa2, va2); fma8(s1, wa3, va3);
        fma8(s2, wc0, vc0); fma8(s2, wc1, vc1);
        fma8(s2, wc2, vc2); fma8(s2, wc3, vc3);
        if (dega > 4) rem4(x2b, csr, sa, ea, fl, s1);
        if (degc > 4) rem4(x2b, csr, sc, ec, fl, s2);
        f4 rlo, rhi;
        #pragma unroll
        for (int k = 0; k < 4; ++k) {
            rlo[k] = 0.25f * (bf2f(x0a[k]) + bf2f(x1a[k]) + bf2f(x2a[k]) + s1[k]);
            rhi[k] = 0.25f * (bf2f(x0a[k + 4]) + bf2f(x1a[k + 4]) + bf2f(x2a[k + 4]) + s1[k + 4]);
        }
        f4* arow = acc + (ll)na * 16;
        __builtin_nontemporal_store(rlo, &arow[fl * 2]);
        __builtin_nontemporal_store(rhi, &arow[fl * 2 + 1]);
        #pragma unroll
        for (int k = 0; k < 4; ++k) {
            rlo[k] = 0.25f * (bf2f(x0c[k]) + bf2f(x1c[k]) + bf2f(x2c[k]) + s2[k]);
            rhi[k] = 0.25f * (bf2f(x0c[k + 4]) + bf2f(x1c[k + 4]) + bf2f(x2c[k + 4]) + s2[k + 4]);
        }
        arow = acc + (ll)nc * 16;
        __builtin_nontemporal_store(rlo, &arow[fl * 2]);
        __builtin_nontemporal_store(rhi, &arow[fl * 2 + 1]);
    }
}

// ---------------------------------------------------------------------------
// Fallback (round-1 atomic path) in case ws is too small.
// ---------------------------------------------------------------------------

__global__ void fb_init(const float* __restrict__ user_w,
                        const float* __restrict__ item_w,
                        float* __restrict__ acc, float* __restrict__ xcur) {
    const ll total4 = (ll)N_NODES * EMB_DIM / 4;
    const ll user4 = (ll)N_USERS * EMB_DIM / 4;
    const float4* uw = (const float4*)user_w;
    const float4* iw = (const float4*)item_w;
    float4* a4 = (float4*)acc;
    float4* x4 = (float4*)xcur;
    ll stride = (ll)gridDim.x * blockDim.x;
    for (ll i = (ll)blockIdx.x * blockDim.x + threadIdx.x; i < total4; i += stride) {
        float4 v = (i < user4) ? uw[i] : iw[i - user4];
        x4[i] = v;
        a4[i] = make_float4(0.25f * v.x, 0.25f * v.y, 0.25f * v.z, 0.25f * v.w);
    }
}
__global__ void fb_zero(float* __restrict__ p) {
    const ll total4 = (ll)N_NODES * EMB_DIM / 4;
    float4* p4 = (float4*)p;
    ll stride = (ll)gridDim.x * blockDim.x;
    float4 z = make_float4(0.f, 0.f, 0.f, 0.f);
    for (ll i = (ll)blockIdx.x * blockDim.x + threadIdx.x; i < total4; i += stride)
        p4[i] = z;
}
__global__ void fb_scatter(const float* __restrict__ xcur, const int* __restrict__ src,
                           const int* __restrict__ dst, const float* __restrict__ w,
                           float* __restrict__ xnext) {
    const int gpb = blockDim.x >> 6;
    const int d = threadIdx.x & 63;
    int eg = blockIdx.x * gpb + (threadIdx.x >> 6);
    const int estride = gridDim.x * gpb;
    for (int e = eg; e < N_EDGES; e += estride) {
        int s = src[e]; int t = dst[e]; float wt = w[e];
        atomicAdd(&xnext[(ll)t * EMB_DIM + d], xcur[(ll)s * EMB_DIM + d] * wt);
    }
}
__global__ void fb_accadd(const float* __restrict__ xn, float* __restrict__ acc) {
    const ll total4 = (ll)N_NODES * EMB_DIM / 4;
    const float4* x4 = (const float4*)xn;
    float4* a4 = (float4*)acc;
    ll stride = (ll)gridDim.x * blockDim.x;
    for (ll i = (ll)blockIdx.x * blockDim.x + threadIdx.x; i < total4; i += stride) {
        float4 v = x4[i]; float4 a = a4[i];
        a.x += 0.25f * v.x; a.y += 0.25f * v.y;
        a.z += 0.25f * v.z; a.w += 0.25f * v.w;
        a4[i] = a;
    }
}

// ---------------------------------------------------------------------------

extern "C" void kernel_launch(void* const* d_in, const int* in_sizes, int n_in,
                              void* d_out, int out_size, void* d_ws, size_t ws_size,
                              hipStream_t stream) {
    const float* user_w = (const float*)d_in[0];
    const float* item_w = (const float*)d_in[1];
    const int*   eidx   = (const int*)d_in[2];     // [2, N_EDGES] int32
    const float* ew     = (const float*)d_in[3];   // [N_EDGES]
    const int* src = eidx;
    const int* dst = eidx + N_EDGES;

    const size_t xb_bf = (size_t)N_NODES * EMB_DIM * 2;          // 64 MB each
    size_t off = 0;
    size_t x0_off     = off;   off += xb_bf;
    size_t x1_off     = off;   off += xb_bf;
    size_t x2_off     = off;   off += xb_bf;
    size_t stage_off  = off;   off += (size_t)NBUCK * BUCK_CAP * 8;   // ~12 MB
    size_t csr_off    = off;   off += (size_t)N_EDGES * 8;            // 9.6 MB
    size_t rowptr_off = off;   off += (size_t)(N_NODES + 1) * 4;      // 2 MB
    size_t gcur_off   = off;   off += 256 * 4;
    size_t bsums_off  = off;   off += 4096;
    const size_t need = off;

    const int blk = 256;

    if (ws_size >= need) {
        us8*   x0b   = (us8*)((char*)d_ws + x0_off);
        us8*   x1b   = (us8*)((char*)d_ws + x1_off);
        us8*   x2b   = (us8*)((char*)d_ws + x2_off);
        uint2* stage = (uint2*)((char*)d_ws + stage_off);
        int2*  csr   = (int2*)((char*)d_ws + csr_off);
        int*   rowptr = (int*)((char*)d_ws + rowptr_off);
        int*   gcur   = (int*)((char*)d_ws + gcur_off);
        int*   bsums  = (int*)((char*)d_ws + bsums_off);
        f4*    acc    = (f4*)d_out;
        const f4* u4 = (const f4*)user_w;
        const f4* i4 = (const f4*)item_w;

        const int nb_scan = (N_NODES + SCAN_ELEMS - 1) / SCAN_ELEMS;  // 489

        // --- CSR build + x0->bf16 conversion (fused/overlapped) ---
        k_init<<<1, 256, 0, stream>>>(gcur);
        k_bsort_conv<<<NB_SORT + NB_CONV, blk, 0, stream>>>(src, dst, ew, gcur,
                                                            stage, u4, i4, x0b);
        k_ncount<<<NBUCK, blk, 0, stream>>>(stage, gcur, rowptr);
        k_scan1<<<nb_scan, 256, 0, stream>>>(rowptr, bsums);
        k_scan2<<<1, 512, 0, stream>>>(bsums, nb_scan);
        k_scan3<<<2048, blk, 0, stream>>>(rowptr, bsums);
        k_place<<<NBUCK, blk, 0, stream>>>(stage, gcur, rowptr, csr);

        // --- layers ---
        const int grid_l = 4096;
        k_prop<<<grid_l, blk, 0, stream>>>(x0b, rowptr, csr, x1b);
        k_prop<<<grid_l, blk, 0, stream>>>(x1b, rowptr, csr, x2b);
        k_final<<<grid_l, blk, 0, stream>>>(x0b, x1b, x2b, rowptr, csr, acc);
    } else {
        float* acc = (float*)d_out;
        float* xcur = (float*)d_ws;
        float* xnext = xcur + (ll)N_NODES * EMB_DIM;
        fb_init<<<2048, blk, 0, stream>>>(user_w, item_w, acc, xcur);
        for (int layer = 0; layer < 3; ++layer) {
            fb_zero<<<2048, blk, 0, stream>>>(xnext);
            fb_scatter<<<4096, blk, 0, stream>>>(xcur, src, dst, ew, xnext);
            fb_accadd<<<2048, blk, 0, stream>>>(xnext, acc);
            float* tmp = xcur; xcur = xnext; xnext = tmp;
        }
    }
}